// Round 11
// baseline (1578.539 us; speedup 1.0000x reference)
//
#include <hip/hip_runtime.h>
#include <math.h>

#define BB 128
#define TT 512
#define FF 16

typedef _Float16 half8 __attribute__((ext_vector_type(8)));
typedef float floatx4 __attribute__((ext_vector_type(4)));

union HU { uint4 u; half8 h; };

__device__ __forceinline__ float bf2f(unsigned short u){
  union { unsigned int i; float f; } c; c.i = ((unsigned int)u) << 16; return c.f;
}
__device__ __forceinline__ unsigned short f2bf(float f){
  union { float f; unsigned int i; } c; c.f = f;
  unsigned int x = c.i;
  unsigned int r = (x + 0x7fffu + ((x >> 16) & 1u)) >> 16;
  return (unsigned short)r;
}
__device__ __forceinline__ float sigm(float x){
  return __builtin_amdgcn_rcpf(1.f + __expf(-x));
}
__device__ __forceinline__ float tanh_fast(float x){
  x = fminf(15.f, fmaxf(-15.f, x));
  float e = __expf(-2.f*x);
  return (1.f - e)*__builtin_amdgcn_rcpf(1.f + e);
}
__device__ __forceinline__ float lrelu(float v){ return v >= 0.f ? v : 0.01f*v; }

__device__ __forceinline__ unsigned int packhl(float v){
  _Float16 hh = (_Float16)v;
  float hf = (float)hh;
  _Float16 hl = (_Float16)(v - hf);
  union { _Float16 h; unsigned short s; } a, b;
  a.h = hh; b.h = hl;
  return (unsigned int)a.s | ((unsigned int)b.s << 16);
}

__device__ __forceinline__ void unpackAB(uint4 P0, uint4 P1, HU& Ah, HU& Al){
  Ah.u.x = (P0.x & 0xffffu) | (P0.y << 16);
  Ah.u.y = (P0.z & 0xffffu) | (P0.w << 16);
  Ah.u.z = (P1.x & 0xffffu) | (P1.y << 16);
  Ah.u.w = (P1.z & 0xffffu) | (P1.w << 16);
  Al.u.x = (P0.x >> 16) | (P0.y & 0xffff0000u);
  Al.u.y = (P0.z >> 16) | (P0.w & 0xffff0000u);
  Al.u.z = (P1.x >> 16) | (P1.y & 0xffff0000u);
  Al.u.w = (P1.z >> 16) | (P1.w & 0xffff0000u);
}

#define MFMA16(A,B,C) __builtin_amdgcn_mfma_f32_16x16x32_f16((A),(B),(C),0,0,0)

// ---------- diagnostic fill ----------
__global__ __launch_bounds__(256) void fill_kernel(unsigned short* out, int n, float v){
  int i = blockIdx.x*256 + threadIdx.x;
  if (i < n) out[i] = f2bf(v);
}

// ---------- dtype autodetect, parallel ----------
__global__ __launch_bounds__(256) void detect1_kernel(const unsigned short* x, float* maxbuf){
  __shared__ float red[256];
  const int base = blockIdx.x*4096 + threadIdx.x*16;
  const uint4* p = (const uint4*)(x + base);
  uint4 a = p[0], b = p[1];
  unsigned int ws[8] = {a.x,a.y,a.z,a.w,b.x,b.y,b.z,b.w};
  float m = 0.f;
  #pragma unroll
  for (int i=0;i<8;i++){
    float v0 = fabsf(bf2f((unsigned short)(ws[i] & 0xffffu)));
    float v1 = fabsf(bf2f((unsigned short)(ws[i] >> 16)));
    if (!isfinite(v0)) v0 = 3e38f;
    if (!isfinite(v1)) v1 = 3e38f;
    m = fmaxf(m, fmaxf(v0, v1));
  }
  red[threadIdx.x] = m; __syncthreads();
  for (int s=128; s>0; s>>=1){
    if (threadIdx.x < s) red[threadIdx.x] = fmaxf(red[threadIdx.x], red[threadIdx.x+s]);
    __syncthreads();
  }
  if (threadIdx.x == 0) maxbuf[blockIdx.x] = red[0];
}
__global__ __launch_bounds__(64) void detect2_kernel(const float* maxbuf, int* flag){
  if (threadIdx.x == 0){
    float m = 0.f;
    for (int i=0;i<32;i++) m = fmaxf(m, maxbuf[i]);
    *flag = (m < 1e4f) ? 1 : 0;
  }
}

// ---------- normalize all inputs to fp32 ----------
struct CvtArgs { const void* p[23]; int sz[23]; int ofs[23]; };

__global__ __launch_bounds__(256) void convert_kernel(CvtArgs a, const int* flag, float* dst){
  const int i = blockIdx.x;
  const int n = a.sz[i];
  const int start = blockIdx.y * 16384;
  if (start >= n) return;
  const int end = (start + 16384 < n) ? start + 16384 : n;
  float* d = dst + a.ofs[i];
  const int s4 = start >> 2, e4 = end >> 2;
  if (*flag){
    const unsigned short* s = (const unsigned short*)a.p[i];
    for (int e = s4 + threadIdx.x; e < e4; e += 256){
      uint2 w = *(const uint2*)(s + 4*e);
      float4 o;
      o.x = bf2f((unsigned short)(w.x & 0xffffu));
      o.y = bf2f((unsigned short)(w.x >> 16));
      o.z = bf2f((unsigned short)(w.y & 0xffffu));
      o.w = bf2f((unsigned short)(w.y >> 16));
      *(float4*)(d + 4*e) = o;
    }
  } else {
    const float* s = (const float*)a.p[i];
    for (int e = s4 + threadIdx.x; e < e4; e += 256)
      *(float4*)(d + 4*e) = *(const float4*)(s + 4*e);
  }
}

// ---------- prep f16 weights ----------
__global__ __launch_bounds__(256) void prep16_kernel(
    const float* __restrict__ cvt, _Float16* __restrict__ h16,
    int o6, int o10, int o14, int o13, int o17, int o19, int o2)
{
  const int i = blockIdx.x*256 + threadIdx.x;
  const int y = blockIdx.y;
  if (y == 0){ if (i < 49152) h16[i]          = (_Float16)cvt[o6  + i]; }
  else if (y == 1){ if (i < 49152) h16[49152 + i]  = (_Float16)cvt[o10 + i]; }
  else if (y == 2){ if (i < 49152) h16[98304 + i]  = (_Float16)cvt[o14 + i]; }
  else if (y == 3){ if (i < 98304) h16[147456 + i] = (_Float16)cvt[o13 + i]; }
  else if (y == 4){
    if (i < 163840){
      int ci = i & 31, co = (i >> 5) & 63, fj = i >> 11;
      int f = fj / 5, j = fj - 5*f;
      h16[245760 + i] = (_Float16)cvt[o17 + ((f*32 + ci)*64 + co)*5 + j];
    }
  } else if (y == 5){
    if (i < 655360){
      int ci = i & 63, co = (i >> 6) & 127, fj = i >> 13;
      int f = fj / 5, j = fj - 5*f;
      h16[409600 + i] = (_Float16)cvt[o19 + ((f*64 + ci)*128 + co)*5 + j];
    }
  } else {
    if (i < 1536){
      int k = i & 31, row = i >> 5;
      h16[1064960 + i] = (k < 16) ? (_Float16)cvt[o2 + row*16 + k] : (_Float16)0.f;
    }
  }
}

// ---------- x transpose ----------
__global__ __launch_bounds__(128) void xt_kernel(const float* __restrict__ cvt, float* __restrict__ xTp){
  const int t = blockIdx.x, b = threadIdx.x;
  xTp[t*BB + b]            = cvt[(b*2 + 0)*TT + t];
  xTp[65536 + t*BB + b]    = cvt[(b*2 + 1)*TT + t];
}

// ---------- Kernel 1: encoder GRU via MFMA — single wave, NO barrier ----------
// state cols <= 15, so [16][24] is in-bounds here (writes col ml, reads cols 8q, q<2)
__global__ __launch_bounds__(64) void enc_kernel(
    const float* __restrict__ xTp, const _Float16* __restrict__ whhE,
    const float* __restrict__ Wih, const float* __restrict__ bih,
    const float* __restrict__ bhh, float* __restrict__ xfeatT)
{
  const int b0 = blockIdx.x*16;
  const int l = threadIdx.x, ml = l & 15, q = l >> 4;
  __shared__ __align__(16) _Float16 HpkH[16][24];
  __shared__ __align__(16) _Float16 HpkL[16][24];
  half8 Bw[3];
  #pragma unroll
  for (int c=0;c<3;c++)
    Bw[c] = *(const half8*)(whhE + (16*c + ml)*32 + 8*q);
  float w0r=Wih[ml*2],      w1r=Wih[ml*2+1],      bir=bih[ml],    bhr=bhh[ml];
  float w0z=Wih[(16+ml)*2], w1z=Wih[(16+ml)*2+1], biz=bih[16+ml], bhz=bhh[16+ml];
  float w0n=Wih[(32+ml)*2], w1n=Wih[(32+ml)*2+1], bin_=bih[32+ml], bhn=bhh[32+ml];
  float hm[4] = {0,0,0,0};
  HU Ah, Al; Ah.u = make_uint4(0,0,0,0); Al.u = Ah.u;
  const floatx4 z4 = {0.f,0.f,0.f,0.f};
  floatx4 x0v = *(const floatx4*)(xTp + b0 + 4*q);
  floatx4 x1v = *(const floatx4*)(xTp + 65536 + b0 + 4*q);
  for (int t=0;t<TT;t++){
    const int tn = (t < 511) ? t+1 : t;
    floatx4 x0n = *(const floatx4*)(xTp + tn*BB + b0 + 4*q);
    floatx4 x1n = *(const floatx4*)(xTp + 65536 + tn*BB + b0 + 4*q);
    floatx4 C[3];
    #pragma unroll
    for (int c=0;c<3;c++){
      C[c] = MFMA16(Al.h, Bw[c], z4);
      C[c] = MFMA16(Ah.h, Bw[c], C[c]);
    }
    float4 hv4;
    #pragma unroll
    for (int r=0;r<4;r++){
      float xb0 = x0v[r], xb1 = x1v[r];
      float rr = sigm(fmaf(w0r,xb0,fmaf(w1r,xb1,bir)) + C[0][r] + bhr);
      float zz = sigm(fmaf(w0z,xb0,fmaf(w1z,xb1,biz)) + C[1][r] + bhz);
      float nn = tanh_fast(fmaf(w0n,xb0,fmaf(w1n,xb1,bin_)) + rr*(C[2][r] + bhn));
      float hn = nn + zz*(hm[r] - nn);
      hm[r] = hn;
      _Float16 hh = (_Float16)hn;
      _Float16 hl = (_Float16)(hn - (float)hh);
      HpkH[4*q + r][ml] = hh;
      HpkL[4*q + r][ml] = hl;
      ((float*)&hv4)[r] = hn;
    }
    *(float4*)(xfeatT + ((size_t)ml*TT + t)*BB + b0 + 4*q) = hv4;
    if (q < 2){
      Ah.u = *(const uint4*)&HpkH[ml][8*q];
      Al.u = *(const uint4*)&HpkL[ml][8*q];
    } else { Ah.u = make_uint4(0,0,0,0); Al.u = Ah.u; }
    x0v = x0n; x1v = x1n;
  }
}

// ---------- Kernel 2 (fallback path): g1 backward (unchanged, proven) ----------
__global__ __launch_bounds__(128) void g1b_kernel(
    const float* __restrict__ xT, const _Float16* __restrict__ whh_h,
    const float* __restrict__ wih, const float* __restrict__ bih,
    const float* __restrict__ bhh, _Float16* __restrict__ trace)
{
  const int f = blockIdx.x, b0 = blockIdx.y*16;
  const int wid = threadIdx.x >> 6, l = threadIdx.x & 63, ml = l & 15, q = l >> 4;
  __shared__ unsigned int Hpk[2][16][36];
  half8 Bw[3];
  #pragma unroll
  for (int i=0;i<3;i++){
    int tc = 2*i + wid;
    Bw[i] = *(const half8*)(whh_h + (size_t)f*3072 + (16*tc + ml)*32 + 8*q);
  }
  const int j = 16*wid + ml, base = f*96;
  float wir=wih[base+j], wiz=wih[base+32+j], win=wih[base+64+j];
  float br_=bih[base+j]+bhh[base+j];
  float bz_=bih[base+32+j]+bhh[base+32+j];
  float bin_=bih[base+64+j], bhn_=bhh[base+64+j];
  float hm[4] = {0,0,0,0};
  HU Ah, Al; Ah.u = make_uint4(0,0,0,0); Al.u = Ah.u;
  const floatx4 z4 = {0.f,0.f,0.f,0.f};
  int pp = 0;
  floatx4 xv = *(const floatx4*)(xT + ((size_t)f*TT + 511)*BB + b0 + 4*q);
  const int dostore = (wid == (q >> 1));
  for (int s=0;s<512;s++){
    const int t = 511 - s;
    const int tn = (s < 511) ? t-1 : t;
    floatx4 xnx = *(const floatx4*)(xT + ((size_t)f*TT + tn)*BB + b0 + 4*q);
    floatx4 C[3];
    #pragma unroll
    for (int i=0;i<3;i++){
      C[i] = MFMA16(Al.h, Bw[i], z4);
      C[i] = MFMA16(Ah.h, Bw[i], C[i]);
    }
    #pragma unroll
    for (int r=0;r<4;r++){
      float xb = xv[r];
      float rr = sigm(fmaf(wir, xb, br_) + C[0][r]);
      float zz = sigm(fmaf(wiz, xb, bz_) + C[1][r]);
      float nn = tanh_fast(fmaf(win, xb, bin_) + rr*(C[2][r] + bhn_));
      float hn = nn + zz*(hm[r] - nn);
      hm[r] = hn;
      Hpk[pp][4*q + r][j] = packhl(hn);
    }
    __syncthreads();
    {
      uint4 P0 = *(const uint4*)&Hpk[pp][ml][8*q];
      uint4 P1 = *(const uint4*)&Hpk[pp][ml][8*q + 4];
      unpackAB(P0, P1, Ah, Al);
    }
    if (dostore)
      *(uint4*)(trace + (((size_t)(f*BB + b0 + ml))*TT + t)*32 + 8*q) = Ah.u;
    pp ^= 1;
    xv = xnx;
  }
}

// ---------- Kernel 2b (big-ws): g1 bwd+fwd — single wave, NO barrier ----------
// FIX r10 bug: state cols go to 31 -> arrays must be [16][40] (stride 80B), not [16][24].
__global__ __launch_bounds__(64) void g1bf_kernel(
    const float* __restrict__ xT,
    const _Float16* __restrict__ whhB_h, const float* __restrict__ wihB,
    const float* __restrict__ bihB, const float* __restrict__ bhhB,
    const _Float16* __restrict__ whhF_h, const float* __restrict__ wihF,
    const float* __restrict__ bihF, const float* __restrict__ bhhF,
    _Float16* __restrict__ traceB, _Float16* __restrict__ traceF)
{
  const int f = blockIdx.x, b0 = blockIdx.y*16, dir = blockIdx.z;
  const _Float16* whh_h = dir ? whhF_h : whhB_h;
  const float* wih = dir ? wihF : wihB;
  const float* bih = dir ? bihF : bihB;
  const float* bhh = dir ? bhhF : bhhB;
  _Float16* trace = dir ? traceF : traceB;
  const int l = threadIdx.x, ml = l & 15, q = l >> 4;
  __shared__ __align__(16) _Float16 HpkH[16][40];
  __shared__ __align__(16) _Float16 HpkL[16][40];
  half8 Bw[6];
  #pragma unroll
  for (int c=0;c<6;c++)
    Bw[c] = *(const half8*)(whh_h + (size_t)f*3072 + (16*c + ml)*32 + 8*q);
  const int base = f*96;
  float wir[2], wiz[2], win[2], br_[2], bz_[2], bin_[2], bhn_[2];
  #pragma unroll
  for (int cp=0;cp<2;cp++){
    int j = 16*cp + ml;
    wir[cp]=wih[base+j]; wiz[cp]=wih[base+32+j]; win[cp]=wih[base+64+j];
    br_[cp]=bih[base+j]+bhh[base+j];
    bz_[cp]=bih[base+32+j]+bhh[base+32+j];
    bin_[cp]=bih[base+64+j]; bhn_[cp]=bhh[base+64+j];
  }
  float hm[2][4] = {{0,0,0,0},{0,0,0,0}};
  HU Ah, Al; Ah.u = make_uint4(0,0,0,0); Al.u = Ah.u;
  const floatx4 z4 = {0.f,0.f,0.f,0.f};
  const int tfirst = dir ? 0 : 511;
  floatx4 xv = *(const floatx4*)(xT + ((size_t)f*TT + tfirst)*BB + b0 + 4*q);
  for (int s=0;s<512;s++){
    const int t  = dir ? s : 511 - s;
    const int sn = (s < 511) ? s+1 : s;
    const int tn = dir ? sn : 511 - sn;
    floatx4 xnx = *(const floatx4*)(xT + ((size_t)f*TT + tn)*BB + b0 + 4*q);
    floatx4 C[6];
    #pragma unroll
    for (int c=0;c<6;c++){
      C[c] = MFMA16(Al.h, Bw[c], z4);
      C[c] = MFMA16(Ah.h, Bw[c], C[c]);
    }
    #pragma unroll
    for (int cp=0;cp<2;cp++){
      #pragma unroll
      for (int r=0;r<4;r++){
        float xb = xv[r];
        float rr = sigm(fmaf(wir[cp], xb, br_[cp]) + C[cp][r]);
        float zz = sigm(fmaf(wiz[cp], xb, bz_[cp]) + C[2+cp][r]);
        float nn = tanh_fast(fmaf(win[cp], xb, bin_[cp]) + rr*(C[4+cp][r] + bhn_[cp]));
        float hn = nn + zz*(hm[cp][r] - nn);
        hm[cp][r] = hn;
        _Float16 hh = (_Float16)hn;
        _Float16 hl = (_Float16)(hn - (float)hh);
        HpkH[4*q + r][16*cp + ml] = hh;
        HpkL[4*q + r][16*cp + ml] = hl;
      }
    }
    Ah.u = *(const uint4*)&HpkH[ml][8*q];
    Al.u = *(const uint4*)&HpkL[ml][8*q];
    *(uint4*)(trace + (((size_t)(f*BB + b0 + ml))*TT + t)*32 + 8*q) = Ah.u;
    xv = xnx;
  }
}

// ---------- Kernel 3 (fallback path): fused g1f + g2 (unchanged, proven) ----------
__global__ __launch_bounds__(128) void g2_kernel(
    const float* __restrict__ xT,
    const _Float16* __restrict__ wh1_h, const float* __restrict__ wih1,
    const float* __restrict__ bih1, const float* __restrict__ bhh1,
    const _Float16* __restrict__ wh2_h, const _Float16* __restrict__ w2i_h,
    const float* __restrict__ bih2, const float* __restrict__ bhh2,
    _Float16* __restrict__ trace)
{
  const int f = blockIdx.x, b0 = blockIdx.y*16;
  const int wid = threadIdx.x >> 6, l = threadIdx.x & 63, ml = l & 15, q = l >> 4;
  __shared__ unsigned int Hpk1[2][16][36];
  __shared__ unsigned int Hpk2[2][16][36];
  half8 B1[3], Bh2[3], Bx0[3], Bx1[3];
  #pragma unroll
  for (int i=0;i<3;i++){
    int tc = 2*i + wid;
    B1[i]  = *(const half8*)(wh1_h + (size_t)f*3072 + (16*tc + ml)*32 + 8*q);
    Bh2[i] = *(const half8*)(wh2_h + (size_t)f*3072 + (16*tc + ml)*32 + 8*q);
    Bx0[i] = *(const half8*)(w2i_h + (size_t)f*6144 + (16*tc + ml)*64 + 8*q);
    Bx1[i] = *(const half8*)(w2i_h + (size_t)f*6144 + (16*tc + ml)*64 + 32 + 8*q);
  }
  const int j = 16*wid + ml, base = f*96;
  float wir=wih1[base+j], wiz=wih1[base+32+j], win=wih1[base+64+j];
  float br1_=bih1[base+j]+bhh1[base+j];
  float bz1_=bih1[base+32+j]+bhh1[base+32+j];
  float bin1_=bih1[base+64+j], bhn1_=bhh1[base+64+j];
  float br2_=bih2[base+j]+bhh2[base+j];
  float bz2_=bih2[base+32+j]+bhh2[base+32+j];
  float bin2_=bih2[base+64+j], bhn2_=bhh2[base+64+j];
  float h1[4] = {0,0,0,0};
  float h2[4] = {0,0,0,0};
  HU A1h, A1l, A2h, A2l;
  A1h.u = make_uint4(0,0,0,0); A1l.u = A1h.u; A2h.u = A1h.u; A2l.u = A1h.u;
  const floatx4 z4 = {0.f,0.f,0.f,0.f};
  const size_t rowb = ((size_t)(f*BB + b0 + ml))*TT;
  const int dostore = (wid == (q >> 1));

  {
    floatx4 x0v = *(const floatx4*)(xT + (size_t)f*TT*BB + b0 + 4*q);
    #pragma unroll
    for (int r=0;r<4;r++){
      float xb = x0v[r];
      float rr = sigm(fmaf(wir, xb, br1_));
      float zz = sigm(fmaf(wiz, xb, bz1_));
      float nn = tanh_fast(fmaf(win, xb, bin1_) + rr*bhn1_);
      float hn = (1.f - zz)*nn;
      h1[r] = hn;
      Hpk1[0][4*q + r][j] = packhl(hn);
    }
    __syncthreads();
    uint4 P0 = *(const uint4*)&Hpk1[0][ml][8*q];
    uint4 P1 = *(const uint4*)&Hpk1[0][ml][8*q + 4];
    unpackAB(P0, P1, A1h, A1l);
  }
  int pp = 1;
  uint4 Ub = *(const uint4*)(trace + (rowb + 0)*32 + 8*q);
  floatx4 xv = *(const floatx4*)(xT + ((size_t)f*TT + 1)*BB + b0 + 4*q);
  for (int t=0;t<512;t++){
    const int tn1 = (t < 511) ? t+1 : t;
    const int tn2 = (t < 510) ? t+2 : 511;
    uint4 Ubn = *(const uint4*)(trace + (rowb + tn1)*32 + 8*q);
    floatx4 xnx = *(const floatx4*)(xT + ((size_t)f*TT + tn2)*BB + b0 + 4*q);
    floatx4 C1[3];
    #pragma unroll
    for (int i=0;i<3;i++){
      C1[i] = MFMA16(A1l.h, B1[i], z4);
      C1[i] = MFMA16(A1h.h, B1[i], C1[i]);
    }
    HU Abw; Abw.u = Ub;
    floatx4 Cr, Cz, Cnh, Cnx;
    Cr = MFMA16(A2l.h, Bh2[0], z4); Cr = MFMA16(A2h.h, Bh2[0], Cr);
    Cr = MFMA16(A1l.h, Bx0[0], Cr); Cr = MFMA16(A1h.h, Bx0[0], Cr);
    Cr = MFMA16(Abw.h, Bx1[0], Cr);
    Cz = MFMA16(A2l.h, Bh2[1], z4); Cz = MFMA16(A2h.h, Bh2[1], Cz);
    Cz = MFMA16(A1l.h, Bx0[1], Cz); Cz = MFMA16(A1h.h, Bx0[1], Cz);
    Cz = MFMA16(Abw.h, Bx1[1], Cz);
    Cnh = MFMA16(A2l.h, Bh2[2], z4); Cnh = MFMA16(A2h.h, Bh2[2], Cnh);
    Cnx = MFMA16(A1l.h, Bx0[2], z4); Cnx = MFMA16(A1h.h, Bx0[2], Cnx);
    Cnx = MFMA16(Abw.h, Bx1[2], Cnx);
    #pragma unroll
    for (int r=0;r<4;r++){
      float xb = xv[r];
      float rr1 = sigm(fmaf(wir, xb, br1_) + C1[0][r]);
      float zz1 = sigm(fmaf(wiz, xb, bz1_) + C1[1][r]);
      float nn1 = tanh_fast(fmaf(win, xb, bin1_) + rr1*(C1[2][r] + bhn1_));
      float hn1 = nn1 + zz1*(h1[r] - nn1);
      h1[r] = hn1;
      Hpk1[pp][4*q + r][j] = packhl(hn1);

      float rr2 = sigm(Cr[r] + br2_);
      float zz2 = sigm(Cz[r] + bz2_);
      float nn2 = tanh_fast(Cnx[r] + bin2_ + rr2*(Cnh[r] + bhn2_));
      float hn2 = nn2 + zz2*(h2[r] - nn2);
      h2[r] = hn2;
      Hpk2[pp][4*q + r][j] = packhl(hn2);
    }
    __syncthreads();
    {
      uint4 P0 = *(const uint4*)&Hpk1[pp][ml][8*q];
      uint4 P1 = *(const uint4*)&Hpk1[pp][ml][8*q + 4];
      unpackAB(P0, P1, A1h, A1l);
      uint4 Q0 = *(const uint4*)&Hpk2[pp][ml][8*q];
      uint4 Q1 = *(const uint4*)&Hpk2[pp][ml][8*q + 4];
      unpackAB(Q0, Q1, A2h, A2l);
    }
    if (dostore)
      *(uint4*)(trace + (rowb + t)*32 + 8*q) = A2h.u;
    Ub = Ubn; xv = xnx; pp ^= 1;
  }
}

// ---------- Kernel 3b (big-ws): g2 only — single wave, NO barrier, 2-step prefetch ----------
// FIX r10 bug: [16][40] (state cols reach 31).
__global__ __launch_bounds__(64) void g2f_kernel(
    const _Float16* __restrict__ wh2_h, const _Float16* __restrict__ w2i_h,
    const float* __restrict__ bih2, const float* __restrict__ bhh2,
    const _Float16* __restrict__ traceF, _Float16* __restrict__ traceB)
{
  const int f = blockIdx.x, b0 = blockIdx.y*16;
  const int l = threadIdx.x, ml = l & 15, q = l >> 4;
  __shared__ __align__(16) _Float16 HpkH[16][40];
  __shared__ __align__(16) _Float16 HpkL[16][40];
  half8 Bh2[6], Bx0[6], Bx1[6];
  #pragma unroll
  for (int c=0;c<6;c++){
    Bh2[c] = *(const half8*)(wh2_h + (size_t)f*3072 + (16*c + ml)*32 + 8*q);
    Bx0[c] = *(const half8*)(w2i_h + (size_t)f*6144 + (16*c + ml)*64 + 8*q);
    Bx1[c] = *(const half8*)(w2i_h + (size_t)f*6144 + (16*c + ml)*64 + 32 + 8*q);
  }
  const int base = f*96;
  float br2_[2], bz2_[2], bin2_[2], bhn2_[2];
  #pragma unroll
  for (int cp=0;cp<2;cp++){
    int j = 16*cp + ml;
    br2_[cp]=bih2[base+j]+bhh2[base+j];
    bz2_[cp]=bih2[base+32+j]+bhh2[base+32+j];
    bin2_[cp]=bih2[base+64+j]; bhn2_[cp]=bhh2[base+64+j];
  }
  float h2[2][4] = {{0,0,0,0},{0,0,0,0}};
  HU A2h, A2l; A2h.u = make_uint4(0,0,0,0); A2l.u = A2h.u;
  const floatx4 z4 = {0.f,0.f,0.f,0.f};
  const size_t rowb = ((size_t)(f*BB + b0 + ml))*TT;
  uint4 F0 = *(const uint4*)(traceF + (rowb + 0)*32 + 8*q);
  uint4 F1 = *(const uint4*)(traceF + (rowb + 1)*32 + 8*q);
  uint4 B0 = *(const uint4*)(traceB + (rowb + 0)*32 + 8*q);
  uint4 B1 = *(const uint4*)(traceB + (rowb + 1)*32 + 8*q);
  for (int t=0;t<512;t++){
    const int tn = (t < 510) ? t+2 : 511;
    uint4 F2 = *(const uint4*)(traceF + (rowb + tn)*32 + 8*q);
    uint4 B2 = *(const uint4*)(traceB + (rowb + tn)*32 + 8*q);
    HU AF; AF.u = F0;
    HU AB; AB.u = B0;
    floatx4 Crz[4], Cnh[2], Cnx[2];
    #pragma unroll
    for (int c=0;c<4;c++){
      floatx4 CA = MFMA16(A2l.h, Bh2[c], z4); CA = MFMA16(A2h.h, Bh2[c], CA);
      floatx4 CB = MFMA16(AF.h, Bx0[c], z4);  CB = MFMA16(AB.h, Bx1[c], CB);
      Crz[c] = CA + CB;
    }
    #pragma unroll
    for (int ci=0;ci<2;ci++){
      int c = 4 + ci;
      floatx4 ah = MFMA16(A2l.h, Bh2[c], z4); ah = MFMA16(A2h.h, Bh2[c], ah);
      Cnh[ci] = ah;
      floatx4 ax = MFMA16(AF.h, Bx0[c], z4);  ax = MFMA16(AB.h, Bx1[c], ax);
      Cnx[ci] = ax;
    }
    #pragma unroll
    for (int cp=0;cp<2;cp++){
      #pragma unroll
      for (int r=0;r<4;r++){
        float rr2 = sigm(Crz[cp][r] + br2_[cp]);
        float zz2 = sigm(Crz[2+cp][r] + bz2_[cp]);
        float nn2 = tanh_fast(Cnx[cp][r] + bin2_[cp] + rr2*(Cnh[cp][r] + bhn2_[cp]));
        float hn2 = nn2 + zz2*(h2[cp][r] - nn2);
        h2[cp][r] = hn2;
        _Float16 hh = (_Float16)hn2;
        _Float16 hl = (_Float16)(hn2 - (float)hh);
        HpkH[4*q + r][16*cp + ml] = hh;
        HpkL[4*q + r][16*cp + ml] = hl;
      }
    }
    A2h.u = *(const uint4*)&HpkH[ml][8*q];
    A2l.u = *(const uint4*)&HpkL[ml][8*q];
    *(uint4*)(traceB + (rowb + t)*32 + 8*q) = A2h.u;   // u2 over consumed u1b[t]
    F0 = F1; F1 = F2; B0 = B1; B1 = B2;
  }
}

// ---------- Kernel 4: convT chain via MFMA, W=64 tile (unchanged, proven) ----------
#define UTP 40
#define C3P 72
#define C2P 136
__global__ __launch_bounds__(256) void conv_kernel(
    const _Float16* __restrict__ u2,
    const _Float16* __restrict__ w3T, const float* __restrict__ b3,
    const _Float16* __restrict__ w2T, const float* __restrict__ b2,
    const float* __restrict__ w1, const float* __restrict__ b1,
    void* __restrict__ outv, const int* __restrict__ flag)
{
  const int t0 = blockIdx.x * 64;
  const int b  = blockIdx.y;
  const int f  = blockIdx.z;
  const int tid = threadIdx.x;
  const int w = tid >> 6, l = tid & 63, ml = l & 15, q = l >> 4;

  __shared__ __align__(16) _Float16 utb[84][UTP];
  __shared__ __align__(16) _Float16 c3T[84][C3P];
  __shared__ __align__(16) _Float16 c2T[68][C2P];
  __shared__ float red[4][64];

  const _Float16* urow = u2 + ((size_t)(f*BB + b)*TT)*32;
  const floatx4 z4 = {0.f,0.f,0.f,0.f};

  for (int k = tid; k < 76*4; k += 256){
    int n = k >> 2, seg = k & 3;
    int tg = t0 - 6 + n;
    uint4 v = make_uint4(0,0,0,0);
    if (tg >= 0 && tg < TT) v = *(const uint4*)(urow + (size_t)tg*32 + seg*8);
    *(uint4*)&utb[n][seg*8] = v;
  }
  __syncthreads();

  {
    half8 A3[5];
    #pragma unroll
    for (int jj=0;jj<5;jj++)
      A3[jj] = *(const half8*)(w3T + (((size_t)f*5 + jj)*64 + 16*w + ml)*32 + 8*q);
    float bv[4];
    #pragma unroll
    for (int r=0;r<4;r++) bv[r] = b3[f*64 + 16*w + 4*q + r];
    #pragma unroll
    for (int nt=0;nt<5;nt++){
      floatx4 acc = z4;
      #pragma unroll
      for (int jj=0;jj<5;jj++){
        half8 Bb = *(const half8*)&utb[16*nt + ml + 4 - jj][8*q];
        acc = MFMA16(A3[jj], Bb, acc);
      }
      int tm = 16*nt + ml;
      if (tm < 72){
        int G = t0 - 4 + tm;
        unsigned int pk[2];
        #pragma unroll
        for (int h=0;h<2;h++){
          float v0 = acc[2*h]   + bv[2*h];   v0 = lrelu(v0);
          float v1 = acc[2*h+1] + bv[2*h+1]; v1 = lrelu(v1);
          if (G < 0 || G >= TT){ v0 = 0.f; v1 = 0.f; }
          union { _Float16 hh; unsigned short s; } c0, c1;
          c0.hh = (_Float16)v0; c1.hh = (_Float16)v1;
          pk[h] = (unsigned int)c0.s | ((unsigned int)c1.s << 16);
        }
        *(uint2*)&c3T[tm][16*w + 4*q] = make_uint2(pk[0], pk[1]);
      }
    }
  }
  __syncthreads();

  {
    half8 A2f[5][2][2];
    #pragma unroll
    for (int jj=0;jj<5;jj++)
      #pragma unroll
      for (int ch=0;ch<2;ch++)
        #pragma unroll
        for (int mi=0;mi<2;mi++)
          A2f[jj][ch][mi] = *(const half8*)(w2T + (((size_t)f*5 + jj)*128 + 16*(2*w+mi) + ml)*64 + 32*ch + 8*q);
    float bv2[2][4];
    #pragma unroll
    for (int mi=0;mi<2;mi++)
      #pragma unroll
      for (int r=0;r<4;r++) bv2[mi][r] = b2[f*128 + 16*(2*w+mi) + 4*q + r];
    #pragma unroll
    for (int nt=0;nt<5;nt++){
      floatx4 a0 = z4, a1 = z4;
      #pragma unroll
      for (int jj=0;jj<5;jj++){
        #pragma unroll
        for (int ch=0;ch<2;ch++){
          half8 Bb = *(const half8*)&c3T[16*nt + ml + 4 - jj][32*ch + 8*q];
          a0 = MFMA16(A2f[jj][ch][0], Bb, a0);
          a1 = MFMA16(A2f[jj][ch][1], Bb, a1);
        }
      }
      int p = 16*nt + ml;
      if (p < 68){
        int G = t0 - 2 + p;
        #pragma unroll
        for (int mi=0;mi<2;mi++){
          unsigned int pk[2];
          #pragma unroll
          for (int h=0;h<2;h++){
            float v0 = (mi ? a1[2*h]   : a0[2*h])   + bv2[mi][2*h];   v0 = lrelu(v0);
            float v1 = (mi ? a1[2*h+1] : a0[2*h+1]) + bv2[mi][2*h+1]; v1 = lrelu(v1);
            if (G < 0 || G >= TT){ v0 = 0.f; v1 = 0.f; }
            union { _Float16 hh; unsigned short s; } c0, c1;
            c0.hh = (_Float16)v0; c1.hh = (_Float16)v1;
            pk[h] = (unsigned int)c0.s | ((unsigned int)c1.s << 16);
          }
          *(uint2*)&c2T[p][16*(2*w+mi) + 4*q] = make_uint2(pk[0], pk[1]);
        }
      }
    }
  }
  __syncthreads();

  {
    const int tl = tid & 63, cg = tid >> 6;
    const float* wp = w1 + ((size_t)f*128 + cg*32)*5;
    float acc = 0.f;
    #pragma unroll
    for (int jj=0;jj<5;jj++){
      int row = tl + 4 - jj;
      union { uint4 u; _Float16 h[8]; } u0, u1, u2_, u3;
      u0.u  = *(const uint4*)&c2T[row][cg*32];
      u1.u  = *(const uint4*)&c2T[row][cg*32 + 8];
      u2_.u = *(const uint4*)&c2T[row][cg*32 + 16];
      u3.u  = *(const uint4*)&c2T[row][cg*32 + 24];
      #pragma unroll
      for (int i=0;i<8;i++){
        acc = fmaf(wp[i*5 + jj],      (float)u0.h[i],  acc);
        acc = fmaf(wp[(8+i)*5 + jj],  (float)u1.h[i],  acc);
        acc = fmaf(wp[(16+i)*5 + jj], (float)u2_.h[i], acc);
        acc = fmaf(wp[(24+i)*5 + jj], (float)u3.h[i],  acc);
      }
    }
    red[cg][tl] = acc;
  }
  __syncthreads();
  if (tid < 64){
    float s = b1[f] + red[0][tid] + red[1][tid] + red[2][tid] + red[3][tid];
    s = lrelu(s);
    size_t oi = ((size_t)b*TT + t0 + tid)*FF + f;
    if (*flag) ((unsigned short*)outv)[oi] = f2bf(s);
    else       ((float*)outv)[oi] = s;
  }
}

extern "C" void kernel_launch(void* const* d_in, const int* in_sizes, int n_in,
                              void* d_out, int out_size, void* d_ws, size_t ws_size,
                              hipStream_t stream)
{
  static const int esz[23] = {
    131072,
    96, 768, 48, 48,
    1536, 49152, 1536, 1536,
    1536, 49152, 1536, 1536,
    98304, 49152, 1536, 1536,
    163840, 1024,
    655360, 2048,
    10240, 16
  };
  const size_t NEED = (size_t)16*1024*1024 + (size_t)64*1024*1024;

  float diag = 0.f;
  if (n_in != 23) diag = 2000.f + n_in;
  else {
    for (int i=0;i<23;i++) if (in_sizes[i] != esz[i]) { diag = 1000.f + i; break; }
    if (diag == 0.f && ws_size < NEED) diag = 500.f + (float)(ws_size >> 20);
  }
  if (diag != 0.f){
    hipLaunchKernelGGL(fill_kernel, dim3((out_size+255)/256), dim3(256), 0, stream,
                       (unsigned short*)d_out, out_size, diag);
    return;
  }

  float* cvt = (float*)d_ws;
  int* flagp = (int*)((char*)d_ws + (5ull<<20));
  float* maxbuf = (float*)((char*)d_ws + (5ull<<20) + 256);
  _Float16* h16 = (_Float16*)((char*)d_ws + (6ull<<20));
  float* xTp = (float*)((char*)d_ws + (9ull<<20));
  float* xfeatT = (float*)((char*)d_ws + (10ull<<20));
  _Float16* trace = (_Float16*)((char*)d_ws + (14ull<<20));     // u1b -> u2 (64 MB)
  _Float16* traceF = (_Float16*)((char*)d_ws + (80ull<<20));    // u1f (64 MB, big-ws only)
  const bool bigws = (ws_size >= (145ull<<20));

  CvtArgs a;
  int ofs = 0;
  for (int i=0;i<23;i++){ a.p[i] = d_in[i]; a.sz[i] = esz[i]; a.ofs[i] = ofs; ofs += esz[i]; }
  const float* c[23];
  for (int i=0;i<23;i++) c[i] = cvt + a.ofs[i];

  hipLaunchKernelGGL(detect1_kernel, dim3(32), dim3(256), 0, stream,
                     (const unsigned short*)d_in[0], maxbuf);
  hipLaunchKernelGGL(detect2_kernel, dim3(1), dim3(64), 0, stream, maxbuf, flagp);
  hipLaunchKernelGGL(convert_kernel, dim3(23, 40), dim3(256), 0, stream, a, flagp, cvt);
  hipLaunchKernelGGL(prep16_kernel, dim3(2560, 7), dim3(256), 0, stream,
                     cvt, h16, a.ofs[6], a.ofs[10], a.ofs[14], a.ofs[13],
                     a.ofs[17], a.ofs[19], a.ofs[2]);
  hipLaunchKernelGGL(xt_kernel, dim3(TT), dim3(BB), 0, stream, cvt, xTp);
  hipLaunchKernelGGL(enc_kernel, dim3(BB/16), dim3(64), 0, stream,
                     xTp, h16 + 1064960, c[1], c[3], c[4], xfeatT);
  if (bigws){
    hipLaunchKernelGGL(g1bf_kernel, dim3(FF, 8, 2), dim3(64), 0, stream,
                       xfeatT,
                       h16 + 49152, c[9], c[11], c[12],    // bwd
                       h16 + 0,     c[5], c[7],  c[8],     // fwd
                       trace, traceF);
    hipLaunchKernelGGL(g2f_kernel, dim3(FF, 8), dim3(64), 0, stream,
                       h16 + 98304, h16 + 147456, c[15], c[16],
                       traceF, trace);
  } else {
    hipLaunchKernelGGL(g1b_kernel, dim3(FF, 8), dim3(128), 0, stream,
                       xfeatT, h16 + 49152, c[9], c[11], c[12], trace);
    hipLaunchKernelGGL(g2_kernel, dim3(FF, 8), dim3(128), 0, stream,
                       xfeatT, h16 + 0, c[5], c[7], c[8],
                       h16 + 98304, h16 + 147456, c[15], c[16], trace);
  }
  hipLaunchKernelGGL(conv_kernel, dim3(TT/64, BB, FF), dim3(256), 0, stream,
                     trace, h16 + 245760, c[18], h16 + 409600, c[20], c[21], c[22],
                     d_out, flagp);
}

// Round 12
// 1330.791 us; speedup vs baseline: 1.1862x; 1.1862x over previous
//
#include <hip/hip_runtime.h>
#include <math.h>

#define BB 128
#define TT 512
#define FF 16

typedef _Float16 half8 __attribute__((ext_vector_type(8)));
typedef float floatx4 __attribute__((ext_vector_type(4)));

union HU { uint4 u; half8 h; };

__device__ __forceinline__ float bf2f(unsigned short u){
  union { unsigned int i; float f; } c; c.i = ((unsigned int)u) << 16; return c.f;
}
__device__ __forceinline__ unsigned short f2bf(float f){
  union { float f; unsigned int i; } c; c.f = f;
  unsigned int x = c.i;
  unsigned int r = (x + 0x7fffu + ((x >> 16) & 1u)) >> 16;
  return (unsigned short)r;
}
__device__ __forceinline__ float sigm(float x){
  return __builtin_amdgcn_rcpf(1.f + __expf(-x));
}
__device__ __forceinline__ float tanh_fast(float x){
  x = fminf(15.f, fmaxf(-15.f, x));
  float e = __expf(-2.f*x);
  return (1.f - e)*__builtin_amdgcn_rcpf(1.f + e);
}
__device__ __forceinline__ float lrelu(float v){ return v >= 0.f ? v : 0.01f*v; }

__device__ __forceinline__ unsigned int packhl(float v){
  _Float16 hh = (_Float16)v;
  float hf = (float)hh;
  _Float16 hl = (_Float16)(v - hf);
  union { _Float16 h; unsigned short s; } a, b;
  a.h = hh; b.h = hl;
  return (unsigned int)a.s | ((unsigned int)b.s << 16);
}

__device__ __forceinline__ void unpackAB(uint4 P0, uint4 P1, HU& Ah, HU& Al){
  Ah.u.x = (P0.x & 0xffffu) | (P0.y << 16);
  Ah.u.y = (P0.z & 0xffffu) | (P0.w << 16);
  Ah.u.z = (P1.x & 0xffffu) | (P1.y << 16);
  Ah.u.w = (P1.z & 0xffffu) | (P1.w << 16);
  Al.u.x = (P0.x >> 16) | (P0.y & 0xffff0000u);
  Al.u.y = (P0.z >> 16) | (P0.w & 0xffff0000u);
  Al.u.z = (P1.x >> 16) | (P1.y & 0xffff0000u);
  Al.u.w = (P1.z >> 16) | (P1.w & 0xffff0000u);
}

// lightweight barrier: order LDS only (lgkmcnt(0)), leave global ops in flight.
// Avoids __syncthreads()'s implicit s_waitcnt vmcnt(0) drain that killed the
// prefetch slack in the r9 2-wave version.
__device__ __forceinline__ void lb(){
  asm volatile("s_waitcnt lgkmcnt(0)\n\ts_barrier" ::: "memory");
}

#define MFMA16(A,B,C) __builtin_amdgcn_mfma_f32_16x16x32_f16((A),(B),(C),0,0,0)

// ---------- diagnostic fill ----------
__global__ __launch_bounds__(256) void fill_kernel(unsigned short* out, int n, float v){
  int i = blockIdx.x*256 + threadIdx.x;
  if (i < n) out[i] = f2bf(v);
}

// ---------- dtype autodetect, parallel ----------
__global__ __launch_bounds__(256) void detect1_kernel(const unsigned short* x, float* maxbuf){
  __shared__ float red[256];
  const int base = blockIdx.x*4096 + threadIdx.x*16;
  const uint4* p = (const uint4*)(x + base);
  uint4 a = p[0], b = p[1];
  unsigned int ws[8] = {a.x,a.y,a.z,a.w,b.x,b.y,b.z,b.w};
  float m = 0.f;
  #pragma unroll
  for (int i=0;i<8;i++){
    float v0 = fabsf(bf2f((unsigned short)(ws[i] & 0xffffu)));
    float v1 = fabsf(bf2f((unsigned short)(ws[i] >> 16)));
    if (!isfinite(v0)) v0 = 3e38f;
    if (!isfinite(v1)) v1 = 3e38f;
    m = fmaxf(m, fmaxf(v0, v1));
  }
  red[threadIdx.x] = m; __syncthreads();
  for (int s=128; s>0; s>>=1){
    if (threadIdx.x < s) red[threadIdx.x] = fmaxf(red[threadIdx.x], red[threadIdx.x+s]);
    __syncthreads();
  }
  if (threadIdx.x == 0) maxbuf[blockIdx.x] = red[0];
}
__global__ __launch_bounds__(64) void detect2_kernel(const float* maxbuf, int* flag){
  if (threadIdx.x == 0){
    float m = 0.f;
    for (int i=0;i<32;i++) m = fmaxf(m, maxbuf[i]);
    *flag = (m < 1e4f) ? 1 : 0;
  }
}

// ---------- normalize all inputs to fp32 ----------
struct CvtArgs { const void* p[23]; int sz[23]; int ofs[23]; };

__global__ __launch_bounds__(256) void convert_kernel(CvtArgs a, const int* flag, float* dst){
  const int i = blockIdx.x;
  const int n = a.sz[i];
  const int start = blockIdx.y * 16384;
  if (start >= n) return;
  const int end = (start + 16384 < n) ? start + 16384 : n;
  float* d = dst + a.ofs[i];
  const int s4 = start >> 2, e4 = end >> 2;
  if (*flag){
    const unsigned short* s = (const unsigned short*)a.p[i];
    for (int e = s4 + threadIdx.x; e < e4; e += 256){
      uint2 w = *(const uint2*)(s + 4*e);
      float4 o;
      o.x = bf2f((unsigned short)(w.x & 0xffffu));
      o.y = bf2f((unsigned short)(w.x >> 16));
      o.z = bf2f((unsigned short)(w.y & 0xffffu));
      o.w = bf2f((unsigned short)(w.y >> 16));
      *(float4*)(d + 4*e) = o;
    }
  } else {
    const float* s = (const float*)a.p[i];
    for (int e = s4 + threadIdx.x; e < e4; e += 256)
      *(float4*)(d + 4*e) = *(const float4*)(s + 4*e);
  }
}

// ---------- prep f16 weights ----------
__global__ __launch_bounds__(256) void prep16_kernel(
    const float* __restrict__ cvt, _Float16* __restrict__ h16,
    int o6, int o10, int o14, int o13, int o17, int o19, int o2)
{
  const int i = blockIdx.x*256 + threadIdx.x;
  const int y = blockIdx.y;
  if (y == 0){ if (i < 49152) h16[i]          = (_Float16)cvt[o6  + i]; }
  else if (y == 1){ if (i < 49152) h16[49152 + i]  = (_Float16)cvt[o10 + i]; }
  else if (y == 2){ if (i < 49152) h16[98304 + i]  = (_Float16)cvt[o14 + i]; }
  else if (y == 3){ if (i < 98304) h16[147456 + i] = (_Float16)cvt[o13 + i]; }
  else if (y == 4){
    if (i < 163840){
      int ci = i & 31, co = (i >> 5) & 63, fj = i >> 11;
      int f = fj / 5, j = fj - 5*f;
      h16[245760 + i] = (_Float16)cvt[o17 + ((f*32 + ci)*64 + co)*5 + j];
    }
  } else if (y == 5){
    if (i < 655360){
      int ci = i & 63, co = (i >> 6) & 127, fj = i >> 13;
      int f = fj / 5, j = fj - 5*f;
      h16[409600 + i] = (_Float16)cvt[o19 + ((f*64 + ci)*128 + co)*5 + j];
    }
  } else {
    if (i < 1536){
      int k = i & 31, row = i >> 5;
      h16[1064960 + i] = (k < 16) ? (_Float16)cvt[o2 + row*16 + k] : (_Float16)0.f;
    }
  }
}

// ---------- x transpose ----------
__global__ __launch_bounds__(128) void xt_kernel(const float* __restrict__ cvt, float* __restrict__ xTp){
  const int t = blockIdx.x, b = threadIdx.x;
  xTp[t*BB + b]            = cvt[(b*2 + 0)*TT + t];
  xTp[65536 + t*BB + b]    = cvt[(b*2 + 1)*TT + t];
}

// ---------- Kernel 1: encoder GRU — single wave, no barrier (proven r11) ----------
__global__ __launch_bounds__(64) void enc_kernel(
    const float* __restrict__ xTp, const _Float16* __restrict__ whhE,
    const float* __restrict__ Wih, const float* __restrict__ bih,
    const float* __restrict__ bhh, float* __restrict__ xfeatT)
{
  const int b0 = blockIdx.x*16;
  const int l = threadIdx.x, ml = l & 15, q = l >> 4;
  __shared__ __align__(16) _Float16 HpkH[16][24];
  __shared__ __align__(16) _Float16 HpkL[16][24];
  half8 Bw[3];
  #pragma unroll
  for (int c=0;c<3;c++)
    Bw[c] = *(const half8*)(whhE + (16*c + ml)*32 + 8*q);
  float w0r=Wih[ml*2],      w1r=Wih[ml*2+1],      bir=bih[ml],    bhr=bhh[ml];
  float w0z=Wih[(16+ml)*2], w1z=Wih[(16+ml)*2+1], biz=bih[16+ml], bhz=bhh[16+ml];
  float w0n=Wih[(32+ml)*2], w1n=Wih[(32+ml)*2+1], bin_=bih[32+ml], bhn=bhh[32+ml];
  float hm[4] = {0,0,0,0};
  HU Ah, Al; Ah.u = make_uint4(0,0,0,0); Al.u = Ah.u;
  const floatx4 z4 = {0.f,0.f,0.f,0.f};
  floatx4 x0v = *(const floatx4*)(xTp + b0 + 4*q);
  floatx4 x1v = *(const floatx4*)(xTp + 65536 + b0 + 4*q);
  for (int t=0;t<TT;t++){
    const int tn = (t < 511) ? t+1 : t;
    floatx4 x0n = *(const floatx4*)(xTp + tn*BB + b0 + 4*q);
    floatx4 x1n = *(const floatx4*)(xTp + 65536 + tn*BB + b0 + 4*q);
    floatx4 C[3];
    #pragma unroll
    for (int c=0;c<3;c++){
      C[c] = MFMA16(Al.h, Bw[c], z4);
      C[c] = MFMA16(Ah.h, Bw[c], C[c]);
    }
    float4 hv4;
    #pragma unroll
    for (int r=0;r<4;r++){
      float xb0 = x0v[r], xb1 = x1v[r];
      float rr = sigm(fmaf(w0r,xb0,fmaf(w1r,xb1,bir)) + C[0][r] + bhr);
      float zz = sigm(fmaf(w0z,xb0,fmaf(w1z,xb1,biz)) + C[1][r] + bhz);
      float nn = tanh_fast(fmaf(w0n,xb0,fmaf(w1n,xb1,bin_)) + rr*(C[2][r] + bhn));
      float hn = nn + zz*(hm[r] - nn);
      hm[r] = hn;
      _Float16 hh = (_Float16)hn;
      _Float16 hl = (_Float16)(hn - (float)hh);
      HpkH[4*q + r][ml] = hh;
      HpkL[4*q + r][ml] = hl;
      ((float*)&hv4)[r] = hn;
    }
    *(float4*)(xfeatT + ((size_t)ml*TT + t)*BB + b0 + 4*q) = hv4;
    if (q < 2){
      Ah.u = *(const uint4*)&HpkH[ml][8*q];
      Al.u = *(const uint4*)&HpkL[ml][8*q];
    } else { Ah.u = make_uint4(0,0,0,0); Al.u = Ah.u; }
    x0v = x0n; x1v = x1n;
  }
}

// ---------- Kernel 2 (fallback path): g1 backward (unchanged, proven) ----------
__global__ __launch_bounds__(128) void g1b_kernel(
    const float* __restrict__ xT, const _Float16* __restrict__ whh_h,
    const float* __restrict__ wih, const float* __restrict__ bih,
    const float* __restrict__ bhh, _Float16* __restrict__ trace)
{
  const int f = blockIdx.x, b0 = blockIdx.y*16;
  const int wid = threadIdx.x >> 6, l = threadIdx.x & 63, ml = l & 15, q = l >> 4;
  __shared__ unsigned int Hpk[2][16][36];
  half8 Bw[3];
  #pragma unroll
  for (int i=0;i<3;i++){
    int tc = 2*i + wid;
    Bw[i] = *(const half8*)(whh_h + (size_t)f*3072 + (16*tc + ml)*32 + 8*q);
  }
  const int j = 16*wid + ml, base = f*96;
  float wir=wih[base+j], wiz=wih[base+32+j], win=wih[base+64+j];
  float br_=bih[base+j]+bhh[base+j];
  float bz_=bih[base+32+j]+bhh[base+32+j];
  float bin_=bih[base+64+j], bhn_=bhh[base+64+j];
  float hm[4] = {0,0,0,0};
  HU Ah, Al; Ah.u = make_uint4(0,0,0,0); Al.u = Ah.u;
  const floatx4 z4 = {0.f,0.f,0.f,0.f};
  int pp = 0;
  floatx4 xv = *(const floatx4*)(xT + ((size_t)f*TT + 511)*BB + b0 + 4*q);
  const int dostore = (wid == (q >> 1));
  for (int s=0;s<512;s++){
    const int t = 511 - s;
    const int tn = (s < 511) ? t-1 : t;
    floatx4 xnx = *(const floatx4*)(xT + ((size_t)f*TT + tn)*BB + b0 + 4*q);
    floatx4 C[3];
    #pragma unroll
    for (int i=0;i<3;i++){
      C[i] = MFMA16(Al.h, Bw[i], z4);
      C[i] = MFMA16(Ah.h, Bw[i], C[i]);
    }
    #pragma unroll
    for (int r=0;r<4;r++){
      float xb = xv[r];
      float rr = sigm(fmaf(wir, xb, br_) + C[0][r]);
      float zz = sigm(fmaf(wiz, xb, bz_) + C[1][r]);
      float nn = tanh_fast(fmaf(win, xb, bin_) + rr*(C[2][r] + bhn_));
      float hn = nn + zz*(hm[r] - nn);
      hm[r] = hn;
      Hpk[pp][4*q + r][j] = packhl(hn);
    }
    __syncthreads();
    {
      uint4 P0 = *(const uint4*)&Hpk[pp][ml][8*q];
      uint4 P1 = *(const uint4*)&Hpk[pp][ml][8*q + 4];
      unpackAB(P0, P1, Ah, Al);
    }
    if (dostore)
      *(uint4*)(trace + (((size_t)(f*BB + b0 + ml))*TT + t)*32 + 8*q) = Ah.u;
    pp ^= 1;
    xv = xnx;
  }
}

// ---------- Kernel 2b (big-ws): g1 bwd+fwd — 2 waves, LIGHT barrier ----------
// r9's proven 2-wave N-split + hi/lo LDS; __syncthreads -> lb() so trace
// stores / x prefetch never drain at the barrier.
__global__ __launch_bounds__(128) void g1bf_kernel(
    const float* __restrict__ xT,
    const _Float16* __restrict__ whhB_h, const float* __restrict__ wihB,
    const float* __restrict__ bihB, const float* __restrict__ bhhB,
    const _Float16* __restrict__ whhF_h, const float* __restrict__ wihF,
    const float* __restrict__ bihF, const float* __restrict__ bhhF,
    _Float16* __restrict__ traceB, _Float16* __restrict__ traceF)
{
  const int f = blockIdx.x, b0 = blockIdx.y*16, dir = blockIdx.z;
  const _Float16* whh_h = dir ? whhF_h : whhB_h;
  const float* wih = dir ? wihF : wihB;
  const float* bih = dir ? bihF : bihB;
  const float* bhh = dir ? bhhF : bhhB;
  _Float16* trace = dir ? traceF : traceB;
  const int wid = threadIdx.x >> 6, l = threadIdx.x & 63, ml = l & 15, q = l >> 4;
  __shared__ __align__(16) _Float16 HpkH[2][16][40];
  __shared__ __align__(16) _Float16 HpkL[2][16][40];
  half8 Bw[3];
  #pragma unroll
  for (int i=0;i<3;i++){
    int tc = 2*i + wid;
    Bw[i] = *(const half8*)(whh_h + (size_t)f*3072 + (16*tc + ml)*32 + 8*q);
  }
  const int j = 16*wid + ml, base = f*96;
  float wir=wih[base+j], wiz=wih[base+32+j], win=wih[base+64+j];
  float br_=bih[base+j]+bhh[base+j];
  float bz_=bih[base+32+j]+bhh[base+32+j];
  float bin_=bih[base+64+j], bhn_=bhh[base+64+j];
  float hm[4] = {0,0,0,0};
  HU Ah, Al; Ah.u = make_uint4(0,0,0,0); Al.u = Ah.u;
  const floatx4 z4 = {0.f,0.f,0.f,0.f};
  int pp = 0;
  const int tfirst = dir ? 0 : 511;
  floatx4 xv = *(const floatx4*)(xT + ((size_t)f*TT + tfirst)*BB + b0 + 4*q);
  const int dostore = (wid == (q >> 1));
  for (int s=0;s<512;s++){
    const int t  = dir ? s : 511 - s;
    const int sn = (s < 511) ? s+1 : s;
    const int tn = dir ? sn : 511 - sn;
    floatx4 xnx = *(const floatx4*)(xT + ((size_t)f*TT + tn)*BB + b0 + 4*q);
    floatx4 C[3];
    #pragma unroll
    for (int i=0;i<3;i++){
      C[i] = MFMA16(Al.h, Bw[i], z4);
      C[i] = MFMA16(Ah.h, Bw[i], C[i]);
    }
    #pragma unroll
    for (int r=0;r<4;r++){
      float xb = xv[r];
      float rr = sigm(fmaf(wir, xb, br_) + C[0][r]);
      float zz = sigm(fmaf(wiz, xb, bz_) + C[1][r]);
      float nn = tanh_fast(fmaf(win, xb, bin_) + rr*(C[2][r] + bhn_));
      float hn = nn + zz*(hm[r] - nn);
      hm[r] = hn;
      _Float16 hh = (_Float16)hn;
      _Float16 hl = (_Float16)(hn - (float)hh);
      HpkH[pp][4*q + r][j] = hh;
      HpkL[pp][4*q + r][j] = hl;
    }
    lb();
    Ah.u = *(const uint4*)&HpkH[pp][ml][8*q];
    Al.u = *(const uint4*)&HpkL[pp][ml][8*q];
    if (dostore)
      *(uint4*)(trace + (((size_t)(f*BB + b0 + ml))*TT + t)*32 + 8*q) = Ah.u;
    pp ^= 1;
    xv = xnx;
  }
}

// ---------- Kernel 3 (fallback path): fused g1f + g2 (unchanged, proven) ----------
__global__ __launch_bounds__(128) void g2_kernel(
    const float* __restrict__ xT,
    const _Float16* __restrict__ wh1_h, const float* __restrict__ wih1,
    const float* __restrict__ bih1, const float* __restrict__ bhh1,
    const _Float16* __restrict__ wh2_h, const _Float16* __restrict__ w2i_h,
    const float* __restrict__ bih2, const float* __restrict__ bhh2,
    _Float16* __restrict__ trace)
{
  const int f = blockIdx.x, b0 = blockIdx.y*16;
  const int wid = threadIdx.x >> 6, l = threadIdx.x & 63, ml = l & 15, q = l >> 4;
  __shared__ unsigned int Hpk1[2][16][36];
  __shared__ unsigned int Hpk2[2][16][36];
  half8 B1[3], Bh2[3], Bx0[3], Bx1[3];
  #pragma unroll
  for (int i=0;i<3;i++){
    int tc = 2*i + wid;
    B1[i]  = *(const half8*)(wh1_h + (size_t)f*3072 + (16*tc + ml)*32 + 8*q);
    Bh2[i] = *(const half8*)(wh2_h + (size_t)f*3072 + (16*tc + ml)*32 + 8*q);
    Bx0[i] = *(const half8*)(w2i_h + (size_t)f*6144 + (16*tc + ml)*64 + 8*q);
    Bx1[i] = *(const half8*)(w2i_h + (size_t)f*6144 + (16*tc + ml)*64 + 32 + 8*q);
  }
  const int j = 16*wid + ml, base = f*96;
  float wir=wih1[base+j], wiz=wih1[base+32+j], win=wih1[base+64+j];
  float br1_=bih1[base+j]+bhh1[base+j];
  float bz1_=bih1[base+32+j]+bhh1[base+32+j];
  float bin1_=bih1[base+64+j], bhn1_=bhh1[base+64+j];
  float br2_=bih2[base+j]+bhh2[base+j];
  float bz2_=bih2[base+32+j]+bhh2[base+32+j];
  float bin2_=bih2[base+64+j], bhn2_=bhh2[base+64+j];
  float h1[4] = {0,0,0,0};
  float h2[4] = {0,0,0,0};
  HU A1h, A1l, A2h, A2l;
  A1h.u = make_uint4(0,0,0,0); A1l.u = A1h.u; A2h.u = A1h.u; A2l.u = A1h.u;
  const floatx4 z4 = {0.f,0.f,0.f,0.f};
  const size_t rowb = ((size_t)(f*BB + b0 + ml))*TT;
  const int dostore = (wid == (q >> 1));

  {
    floatx4 x0v = *(const floatx4*)(xT + (size_t)f*TT*BB + b0 + 4*q);
    #pragma unroll
    for (int r=0;r<4;r++){
      float xb = x0v[r];
      float rr = sigm(fmaf(wir, xb, br1_));
      float zz = sigm(fmaf(wiz, xb, bz1_));
      float nn = tanh_fast(fmaf(win, xb, bin1_) + rr*bhn1_);
      float hn = (1.f - zz)*nn;
      h1[r] = hn;
      Hpk1[0][4*q + r][j] = packhl(hn);
    }
    __syncthreads();
    uint4 P0 = *(const uint4*)&Hpk1[0][ml][8*q];
    uint4 P1 = *(const uint4*)&Hpk1[0][ml][8*q + 4];
    unpackAB(P0, P1, A1h, A1l);
  }
  int pp = 1;
  uint4 Ub = *(const uint4*)(trace + (rowb + 0)*32 + 8*q);
  floatx4 xv = *(const floatx4*)(xT + ((size_t)f*TT + 1)*BB + b0 + 4*q);
  for (int t=0;t<512;t++){
    const int tn1 = (t < 511) ? t+1 : t;
    const int tn2 = (t < 510) ? t+2 : 511;
    uint4 Ubn = *(const uint4*)(trace + (rowb + tn1)*32 + 8*q);
    floatx4 xnx = *(const floatx4*)(xT + ((size_t)f*TT + tn2)*BB + b0 + 4*q);
    floatx4 C1[3];
    #pragma unroll
    for (int i=0;i<3;i++){
      C1[i] = MFMA16(A1l.h, B1[i], z4);
      C1[i] = MFMA16(A1h.h, B1[i], C1[i]);
    }
    HU Abw; Abw.u = Ub;
    floatx4 Cr, Cz, Cnh, Cnx;
    Cr = MFMA16(A2l.h, Bh2[0], z4); Cr = MFMA16(A2h.h, Bh2[0], Cr);
    Cr = MFMA16(A1l.h, Bx0[0], Cr); Cr = MFMA16(A1h.h, Bx0[0], Cr);
    Cr = MFMA16(Abw.h, Bx1[0], Cr);
    Cz = MFMA16(A2l.h, Bh2[1], z4); Cz = MFMA16(A2h.h, Bh2[1], Cz);
    Cz = MFMA16(A1l.h, Bx0[1], Cz); Cz = MFMA16(A1h.h, Bx0[1], Cz);
    Cz = MFMA16(Abw.h, Bx1[1], Cz);
    Cnh = MFMA16(A2l.h, Bh2[2], z4); Cnh = MFMA16(A2h.h, Bh2[2], Cnh);
    Cnx = MFMA16(A1l.h, Bx0[2], z4); Cnx = MFMA16(A1h.h, Bx0[2], Cnx);
    Cnx = MFMA16(Abw.h, Bx1[2], Cnx);
    #pragma unroll
    for (int r=0;r<4;r++){
      float xb = xv[r];
      float rr1 = sigm(fmaf(wir, xb, br1_) + C1[0][r]);
      float zz1 = sigm(fmaf(wiz, xb, bz1_) + C1[1][r]);
      float nn1 = tanh_fast(fmaf(win, xb, bin1_) + rr1*(C1[2][r] + bhn1_));
      float hn1 = nn1 + zz1*(h1[r] - nn1);
      h1[r] = hn1;
      Hpk1[pp][4*q + r][j] = packhl(hn1);

      float rr2 = sigm(Cr[r] + br2_);
      float zz2 = sigm(Cz[r] + bz2_);
      float nn2 = tanh_fast(Cnx[r] + bin2_ + rr2*(Cnh[r] + bhn2_));
      float hn2 = nn2 + zz2*(h2[r] - nn2);
      h2[r] = hn2;
      Hpk2[pp][4*q + r][j] = packhl(hn2);
    }
    __syncthreads();
    {
      uint4 P0 = *(const uint4*)&Hpk1[pp][ml][8*q];
      uint4 P1 = *(const uint4*)&Hpk1[pp][ml][8*q + 4];
      unpackAB(P0, P1, A1h, A1l);
      uint4 Q0 = *(const uint4*)&Hpk2[pp][ml][8*q];
      uint4 Q1 = *(const uint4*)&Hpk2[pp][ml][8*q + 4];
      unpackAB(Q0, Q1, A2h, A2l);
    }
    if (dostore)
      *(uint4*)(trace + (rowb + t)*32 + 8*q) = A2h.u;
    Ub = Ubn; xv = xnx; pp ^= 1;
  }
}

// ---------- Kernel 3b (big-ws): g2 only — 2 waves, LIGHT barrier, 2-step prefetch ----------
__global__ __launch_bounds__(128) void g2f_kernel(
    const _Float16* __restrict__ wh2_h, const _Float16* __restrict__ w2i_h,
    const float* __restrict__ bih2, const float* __restrict__ bhh2,
    const _Float16* __restrict__ traceF, _Float16* __restrict__ traceB)
{
  const int f = blockIdx.x, b0 = blockIdx.y*16;
  const int wid = threadIdx.x >> 6, l = threadIdx.x & 63, ml = l & 15, q = l >> 4;
  __shared__ __align__(16) _Float16 HpkH[2][16][40];
  __shared__ __align__(16) _Float16 HpkL[2][16][40];
  half8 Bh2[3], Bx0[3], Bx1[3];
  #pragma unroll
  for (int i=0;i<3;i++){
    int tc = 2*i + wid;
    Bh2[i] = *(const half8*)(wh2_h + (size_t)f*3072 + (16*tc + ml)*32 + 8*q);
    Bx0[i] = *(const half8*)(w2i_h + (size_t)f*6144 + (16*tc + ml)*64 + 8*q);
    Bx1[i] = *(const half8*)(w2i_h + (size_t)f*6144 + (16*tc + ml)*64 + 32 + 8*q);
  }
  const int j = 16*wid + ml, base = f*96;
  float br2_=bih2[base+j]+bhh2[base+j];
  float bz2_=bih2[base+32+j]+bhh2[base+32+j];
  float bin2_=bih2[base+64+j], bhn2_=bhh2[base+64+j];
  float h2[4] = {0,0,0,0};
  HU A2h, A2l; A2h.u = make_uint4(0,0,0,0); A2l.u = A2h.u;
  const floatx4 z4 = {0.f,0.f,0.f,0.f};
  const size_t rowb = ((size_t)(f*BB + b0 + ml))*TT;
  const int dostore = (wid == (q >> 1));
  int pp = 0;
  uint4 F0 = *(const uint4*)(traceF + (rowb + 0)*32 + 8*q);
  uint4 F1 = *(const uint4*)(traceF + (rowb + 1)*32 + 8*q);
  uint4 B0 = *(const uint4*)(traceB + (rowb + 0)*32 + 8*q);
  uint4 B1 = *(const uint4*)(traceB + (rowb + 1)*32 + 8*q);
  for (int t=0;t<512;t++){
    const int tn = (t < 510) ? t+2 : 511;
    uint4 F2 = *(const uint4*)(traceF + (rowb + tn)*32 + 8*q);
    uint4 B2 = *(const uint4*)(traceB + (rowb + tn)*32 + 8*q);
    HU AF; AF.u = F0;
    HU AB; AB.u = B0;
    floatx4 Cr, Cz, Cnh, Cnx;
    {
      floatx4 CrA = MFMA16(A2l.h, Bh2[0], z4); CrA = MFMA16(A2h.h, Bh2[0], CrA);
      floatx4 CrB = MFMA16(AF.h, Bx0[0], z4);  CrB = MFMA16(AB.h, Bx1[0], CrB);
      Cr = CrA + CrB;
      floatx4 CzA = MFMA16(A2l.h, Bh2[1], z4); CzA = MFMA16(A2h.h, Bh2[1], CzA);
      floatx4 CzB = MFMA16(AF.h, Bx0[1], z4);  CzB = MFMA16(AB.h, Bx1[1], CzB);
      Cz = CzA + CzB;
      Cnh = MFMA16(A2l.h, Bh2[2], z4); Cnh = MFMA16(A2h.h, Bh2[2], Cnh);
      Cnx = MFMA16(AF.h, Bx0[2], z4);  Cnx = MFMA16(AB.h, Bx1[2], Cnx);
    }
    #pragma unroll
    for (int r=0;r<4;r++){
      float rr2 = sigm(Cr[r] + br2_);
      float zz2 = sigm(Cz[r] + bz2_);
      float nn2 = tanh_fast(Cnx[r] + bin2_ + rr2*(Cnh[r] + bhn2_));
      float hn2 = nn2 + zz2*(h2[r] - nn2);
      h2[r] = hn2;
      _Float16 hh = (_Float16)hn2;
      _Float16 hl = (_Float16)(hn2 - (float)hh);
      HpkH[pp][4*q + r][j] = hh;
      HpkL[pp][4*q + r][j] = hl;
    }
    lb();
    A2h.u = *(const uint4*)&HpkH[pp][ml][8*q];
    A2l.u = *(const uint4*)&HpkL[pp][ml][8*q];
    if (dostore)
      *(uint4*)(traceB + (rowb + t)*32 + 8*q) = A2h.u;   // u2 over consumed u1b[t]
    F0 = F1; F1 = F2; B0 = B1; B1 = B2; pp ^= 1;
  }
}

// ---------- Kernel 4: convT chain via MFMA, W=64 tile (unchanged, proven) ----------
#define UTP 40
#define C3P 72
#define C2P 136
__global__ __launch_bounds__(256) void conv_kernel(
    const _Float16* __restrict__ u2,
    const _Float16* __restrict__ w3T, const float* __restrict__ b3,
    const _Float16* __restrict__ w2T, const float* __restrict__ b2,
    const float* __restrict__ w1, const float* __restrict__ b1,
    void* __restrict__ outv, const int* __restrict__ flag)
{
  const int t0 = blockIdx.x * 64;
  const int b  = blockIdx.y;
  const int f  = blockIdx.z;
  const int tid = threadIdx.x;
  const int w = tid >> 6, l = tid & 63, ml = l & 15, q = l >> 4;

  __shared__ __align__(16) _Float16 utb[84][UTP];
  __shared__ __align__(16) _Float16 c3T[84][C3P];
  __shared__ __align__(16) _Float16 c2T[68][C2P];
  __shared__ float red[4][64];

  const _Float16* urow = u2 + ((size_t)(f*BB + b)*TT)*32;
  const floatx4 z4 = {0.f,0.f,0.f,0.f};

  for (int k = tid; k < 76*4; k += 256){
    int n = k >> 2, seg = k & 3;
    int tg = t0 - 6 + n;
    uint4 v = make_uint4(0,0,0,0);
    if (tg >= 0 && tg < TT) v = *(const uint4*)(urow + (size_t)tg*32 + seg*8);
    *(uint4*)&utb[n][seg*8] = v;
  }
  __syncthreads();

  {
    half8 A3[5];
    #pragma unroll
    for (int jj=0;jj<5;jj++)
      A3[jj] = *(const half8*)(w3T + (((size_t)f*5 + jj)*64 + 16*w + ml)*32 + 8*q);
    float bv[4];
    #pragma unroll
    for (int r=0;r<4;r++) bv[r] = b3[f*64 + 16*w + 4*q + r];
    #pragma unroll
    for (int nt=0;nt<5;nt++){
      floatx4 acc = z4;
      #pragma unroll
      for (int jj=0;jj<5;jj++){
        half8 Bb = *(const half8*)&utb[16*nt + ml + 4 - jj][8*q];
        acc = MFMA16(A3[jj], Bb, acc);
      }
      int tm = 16*nt + ml;
      if (tm < 72){
        int G = t0 - 4 + tm;
        unsigned int pk[2];
        #pragma unroll
        for (int h=0;h<2;h++){
          float v0 = acc[2*h]   + bv[2*h];   v0 = lrelu(v0);
          float v1 = acc[2*h+1] + bv[2*h+1]; v1 = lrelu(v1);
          if (G < 0 || G >= TT){ v0 = 0.f; v1 = 0.f; }
          union { _Float16 hh; unsigned short s; } c0, c1;
          c0.hh = (_Float16)v0; c1.hh = (_Float16)v1;
          pk[h] = (unsigned int)c0.s | ((unsigned int)c1.s << 16);
        }
        *(uint2*)&c3T[tm][16*w + 4*q] = make_uint2(pk[0], pk[1]);
      }
    }
  }
  __syncthreads();

  {
    half8 A2f[5][2][2];
    #pragma unroll
    for (int jj=0;jj<5;jj++)
      #pragma unroll
      for (int ch=0;ch<2;ch++)
        #pragma unroll
        for (int mi=0;mi<2;mi++)
          A2f[jj][ch][mi] = *(const half8*)(w2T + (((size_t)f*5 + jj)*128 + 16*(2*w+mi) + ml)*64 + 32*ch + 8*q);
    float bv2[2][4];
    #pragma unroll
    for (int mi=0;mi<2;mi++)
      #pragma unroll
      for (int r=0;r<4;r++) bv2[mi][r] = b2[f*128 + 16*(2*w+mi) + 4*q + r];
    #pragma unroll
    for (int nt=0;nt<5;nt++){
      floatx4 a0 = z4, a1 = z4;
      #pragma unroll
      for (int jj=0;jj<5;jj++){
        #pragma unroll
        for (int ch=0;ch<2;ch++){
          half8 Bb = *(const half8*)&c3T[16*nt + ml + 4 - jj][32*ch + 8*q];
          a0 = MFMA16(A2f[jj][ch][0], Bb, a0);
          a1 = MFMA16(A2f[jj][ch][1], Bb, a1);
        }
      }
      int p = 16*nt + ml;
      if (p < 68){
        int G = t0 - 2 + p;
        #pragma unroll
        for (int mi=0;mi<2;mi++){
          unsigned int pk[2];
          #pragma unroll
          for (int h=0;h<2;h++){
            float v0 = (mi ? a1[2*h]   : a0[2*h])   + bv2[mi][2*h];   v0 = lrelu(v0);
            float v1 = (mi ? a1[2*h+1] : a0[2*h+1]) + bv2[mi][2*h+1]; v1 = lrelu(v1);
            if (G < 0 || G >= TT){ v0 = 0.f; v1 = 0.f; }
            union { _Float16 hh; unsigned short s; } c0, c1;
            c0.hh = (_Float16)v0; c1.hh = (_Float16)v1;
            pk[h] = (unsigned int)c0.s | ((unsigned int)c1.s << 16);
          }
          *(uint2*)&c2T[p][16*(2*w+mi) + 4*q] = make_uint2(pk[0], pk[1]);
        }
      }
    }
  }
  __syncthreads();

  {
    const int tl = tid & 63, cg = tid >> 6;
    const float* wp = w1 + ((size_t)f*128 + cg*32)*5;
    float acc = 0.f;
    #pragma unroll
    for (int jj=0;jj<5;jj++){
      int row = tl + 4 - jj;
      union { uint4 u; _Float16 h[8]; } u0, u1, u2_, u3;
      u0.u  = *(const uint4*)&c2T[row][cg*32];
      u1.u  = *(const uint4*)&c2T[row][cg*32 + 8];
      u2_.u = *(const uint4*)&c2T[row][cg*32 + 16];
      u3.u  = *(const uint4*)&c2T[row][cg*32 + 24];
      #pragma unroll
      for (int i=0;i<8;i++){
        acc = fmaf(wp[i*5 + jj],      (float)u0.h[i],  acc);
        acc = fmaf(wp[(8+i)*5 + jj],  (float)u1.h[i],  acc);
        acc = fmaf(wp[(16+i)*5 + jj], (float)u2_.h[i], acc);
        acc = fmaf(wp[(24+i)*5 + jj], (float)u3.h[i],  acc);
      }
    }
    red[cg][tl] = acc;
  }
  __syncthreads();
  if (tid < 64){
    float s = b1[f] + red[0][tid] + red[1][tid] + red[2][tid] + red[3][tid];
    s = lrelu(s);
    size_t oi = ((size_t)b*TT + t0 + tid)*FF + f;
    if (*flag) ((unsigned short*)outv)[oi] = f2bf(s);
    else       ((float*)outv)[oi] = s;
  }
}

extern "C" void kernel_launch(void* const* d_in, const int* in_sizes, int n_in,
                              void* d_out, int out_size, void* d_ws, size_t ws_size,
                              hipStream_t stream)
{
  static const int esz[23] = {
    131072,
    96, 768, 48, 48,
    1536, 49152, 1536, 1536,
    1536, 49152, 1536, 1536,
    98304, 49152, 1536, 1536,
    163840, 1024,
    655360, 2048,
    10240, 16
  };
  const size_t NEED = (size_t)16*1024*1024 + (size_t)64*1024*1024;

  float diag = 0.f;
  if (n_in != 23) diag = 2000.f + n_in;
  else {
    for (int i=0;i<23;i++) if (in_sizes[i] != esz[i]) { diag = 1000.f + i; break; }
    if (diag == 0.f && ws_size < NEED) diag = 500.f + (float)(ws_size >> 20);
  }
  if (diag != 0.f){
    hipLaunchKernelGGL(fill_kernel, dim3((out_size+255)/256), dim3(256), 0, stream,
                       (unsigned short*)d_out, out_size, diag);
    return;
  }

  float* cvt = (float*)d_ws;
  int* flagp = (int*)((char*)d_ws + (5ull<<20));
  float* maxbuf = (float*)((char*)d_ws + (5ull<<20) + 256);
  _Float16* h16 = (_Float16*)((char*)d_ws + (6ull<<20));
  float* xTp = (float*)((char*)d_ws + (9ull<<20));
  float* xfeatT = (float*)((char*)d_ws + (10ull<<20));
  _Float16* trace = (_Float16*)((char*)d_ws + (14ull<<20));     // u1b -> u2 (64 MB)
  _Float16* traceF = (_Float16*)((char*)d_ws + (80ull<<20));    // u1f (64 MB, big-ws only)
  const bool bigws = (ws_size >= (145ull<<20));

  CvtArgs a;
  int ofs = 0;
  for (int i=0;i<23;i++){ a.p[i] = d_in[i]; a.sz[i] = esz[i]; a.ofs[i] = ofs; ofs += esz[i]; }
  const float* c[23];
  for (int i=0;i<23;i++) c[i] = cvt + a.ofs[i];

  hipLaunchKernelGGL(detect1_kernel, dim3(32), dim3(256), 0, stream,
                     (const unsigned short*)d_in[0], maxbuf);
  hipLaunchKernelGGL(detect2_kernel, dim3(1), dim3(64), 0, stream, maxbuf, flagp);
  hipLaunchKernelGGL(convert_kernel, dim3(23, 40), dim3(256), 0, stream, a, flagp, cvt);
  hipLaunchKernelGGL(prep16_kernel, dim3(2560, 7), dim3(256), 0, stream,
                     cvt, h16, a.ofs[6], a.ofs[10], a.ofs[14], a.ofs[13],
                     a.ofs[17], a.ofs[19], a.ofs[2]);
  hipLaunchKernelGGL(xt_kernel, dim3(TT), dim3(BB), 0, stream, cvt, xTp);
  hipLaunchKernelGGL(enc_kernel, dim3(BB/16), dim3(64), 0, stream,
                     xTp, h16 + 1064960, c[1], c[3], c[4], xfeatT);
  if (bigws){
    hipLaunchKernelGGL(g1bf_kernel, dim3(FF, 8, 2), dim3(128), 0, stream,
                       xfeatT,
                       h16 + 49152, c[9], c[11], c[12],    // bwd
                       h16 + 0,     c[5], c[7],  c[8],     // fwd
                       trace, traceF);
    hipLaunchKernelGGL(g2f_kernel, dim3(FF, 8), dim3(128), 0, stream,
                       h16 + 98304, h16 + 147456, c[15], c[16],
                       traceF, trace);
  } else {
    hipLaunchKernelGGL(g1b_kernel, dim3(FF, 8), dim3(128), 0, stream,
                       xfeatT, h16 + 49152, c[9], c[11], c[12], trace);
    hipLaunchKernelGGL(g2_kernel, dim3(FF, 8), dim3(128), 0, stream,
                       xfeatT, h16 + 0, c[5], c[7], c[8],
                       h16 + 98304, h16 + 147456, c[15], c[16], trace);
  }
  hipLaunchKernelGGL(conv_kernel, dim3(TT/64, BB, FF), dim3(256), 0, stream,
                     trace, h16 + 245760, c[18], h16 + 409600, c[20], c[21], c[22],
                     d_out, flagp);
}

// Round 13
// 1289.840 us; speedup vs baseline: 1.2238x; 1.0317x over previous
//
#include <hip/hip_runtime.h>
#include <math.h>

#define BB 128
#define TT 512
#define FF 16

typedef _Float16 half8 __attribute__((ext_vector_type(8)));
typedef float floatx4 __attribute__((ext_vector_type(4)));

union HU { uint4 u; half8 h; };

__device__ __forceinline__ float bf2f(unsigned short u){
  union { unsigned int i; float f; } c; c.i = ((unsigned int)u) << 16; return c.f;
}
__device__ __forceinline__ unsigned short f2bf(float f){
  union { float f; unsigned int i; } c; c.f = f;
  unsigned int x = c.i;
  unsigned int r = (x + 0x7fffu + ((x >> 16) & 1u)) >> 16;
  return (unsigned short)r;
}
__device__ __forceinline__ float sigm(float x){
  return __builtin_amdgcn_rcpf(1.f + __expf(-x));
}
__device__ __forceinline__ float tanh_fast(float x){
  x = fminf(15.f, fmaxf(-15.f, x));
  float e = __expf(-2.f*x);
  return (1.f - e)*__builtin_amdgcn_rcpf(1.f + e);
}
__device__ __forceinline__ float lrelu(float v){ return v >= 0.f ? v : 0.01f*v; }

__device__ __forceinline__ unsigned int packhl(float v){
  _Float16 hh = (_Float16)v;
  float hf = (float)hh;
  _Float16 hl = (_Float16)(v - hf);
  union { _Float16 h; unsigned short s; } a, b;
  a.h = hh; b.h = hl;
  return (unsigned int)a.s | ((unsigned int)b.s << 16);
}

__device__ __forceinline__ void unpackAB(uint4 P0, uint4 P1, HU& Ah, HU& Al){
  Ah.u.x = (P0.x & 0xffffu) | (P0.y << 16);
  Ah.u.y = (P0.z & 0xffffu) | (P0.w << 16);
  Ah.u.z = (P1.x & 0xffffu) | (P1.y << 16);
  Ah.u.w = (P1.z & 0xffffu) | (P1.w << 16);
  Al.u.x = (P0.x >> 16) | (P0.y & 0xffff0000u);
  Al.u.y = (P0.z >> 16) | (P0.w & 0xffff0000u);
  Al.u.z = (P1.x >> 16) | (P1.y & 0xffff0000u);
  Al.u.w = (P1.z >> 16) | (P1.w & 0xffff0000u);
}

// lightweight barrier: order LDS only, leave global ops in flight
__device__ __forceinline__ void lb(){
  asm volatile("s_waitcnt lgkmcnt(0)\n\ts_barrier" ::: "memory");
}

#define MFMA16(A,B,C) __builtin_amdgcn_mfma_f32_16x16x32_f16((A),(B),(C),0,0,0)

// ---------- diagnostic fill ----------
__global__ __launch_bounds__(256) void fill_kernel(unsigned short* out, int n, float v){
  int i = blockIdx.x*256 + threadIdx.x;
  if (i < n) out[i] = f2bf(v);
}

// ---------- dtype autodetect, parallel ----------
__global__ __launch_bounds__(256) void detect1_kernel(const unsigned short* x, float* maxbuf){
  __shared__ float red[256];
  const int base = blockIdx.x*4096 + threadIdx.x*16;
  const uint4* p = (const uint4*)(x + base);
  uint4 a = p[0], b = p[1];
  unsigned int ws[8] = {a.x,a.y,a.z,a.w,b.x,b.y,b.z,b.w};
  float m = 0.f;
  #pragma unroll
  for (int i=0;i<8;i++){
    float v0 = fabsf(bf2f((unsigned short)(ws[i] & 0xffffu)));
    float v1 = fabsf(bf2f((unsigned short)(ws[i] >> 16)));
    if (!isfinite(v0)) v0 = 3e38f;
    if (!isfinite(v1)) v1 = 3e38f;
    m = fmaxf(m, fmaxf(v0, v1));
  }
  red[threadIdx.x] = m; __syncthreads();
  for (int s=128; s>0; s>>=1){
    if (threadIdx.x < s) red[threadIdx.x] = fmaxf(red[threadIdx.x], red[threadIdx.x+s]);
    __syncthreads();
  }
  if (threadIdx.x == 0) maxbuf[blockIdx.x] = red[0];
}
__global__ __launch_bounds__(64) void detect2_kernel(const float* maxbuf, int* flag){
  if (threadIdx.x == 0){
    float m = 0.f;
    for (int i=0;i<32;i++) m = fmaxf(m, maxbuf[i]);
    *flag = (m < 1e4f) ? 1 : 0;
  }
}

// ---------- normalize all inputs to fp32 ----------
struct CvtArgs { const void* p[23]; int sz[23]; int ofs[23]; };

__global__ __launch_bounds__(256) void convert_kernel(CvtArgs a, const int* flag, float* dst){
  const int i = blockIdx.x;
  const int n = a.sz[i];
  const int start = blockIdx.y * 16384;
  if (start >= n) return;
  const int end = (start + 16384 < n) ? start + 16384 : n;
  float* d = dst + a.ofs[i];
  const int s4 = start >> 2, e4 = end >> 2;
  if (*flag){
    const unsigned short* s = (const unsigned short*)a.p[i];
    for (int e = s4 + threadIdx.x; e < e4; e += 256){
      uint2 w = *(const uint2*)(s + 4*e);
      float4 o;
      o.x = bf2f((unsigned short)(w.x & 0xffffu));
      o.y = bf2f((unsigned short)(w.x >> 16));
      o.z = bf2f((unsigned short)(w.y & 0xffffu));
      o.w = bf2f((unsigned short)(w.y >> 16));
      *(float4*)(d + 4*e) = o;
    }
  } else {
    const float* s = (const float*)a.p[i];
    for (int e = s4 + threadIdx.x; e < e4; e += 256)
      *(float4*)(d + 4*e) = *(const float4*)(s + 4*e);
  }
}

// ---------- prep f16 weights ----------
__global__ __launch_bounds__(256) void prep16_kernel(
    const float* __restrict__ cvt, _Float16* __restrict__ h16,
    int o6, int o10, int o14, int o13, int o17, int o19, int o2)
{
  const int i = blockIdx.x*256 + threadIdx.x;
  const int y = blockIdx.y;
  if (y == 0){ if (i < 49152) h16[i]          = (_Float16)cvt[o6  + i]; }
  else if (y == 1){ if (i < 49152) h16[49152 + i]  = (_Float16)cvt[o10 + i]; }
  else if (y == 2){ if (i < 49152) h16[98304 + i]  = (_Float16)cvt[o14 + i]; }
  else if (y == 3){ if (i < 98304) h16[147456 + i] = (_Float16)cvt[o13 + i]; }
  else if (y == 4){
    if (i < 163840){
      int ci = i & 31, co = (i >> 5) & 63, fj = i >> 11;
      int f = fj / 5, j = fj - 5*f;
      h16[245760 + i] = (_Float16)cvt[o17 + ((f*32 + ci)*64 + co)*5 + j];
    }
  } else if (y == 5){
    if (i < 655360){
      int ci = i & 63, co = (i >> 6) & 127, fj = i >> 13;
      int f = fj / 5, j = fj - 5*f;
      h16[409600 + i] = (_Float16)cvt[o19 + ((f*64 + ci)*128 + co)*5 + j];
    }
  } else {
    if (i < 1536){
      int k = i & 31, row = i >> 5;
      h16[1064960 + i] = (k < 16) ? (_Float16)cvt[o2 + row*16 + k] : (_Float16)0.f;
    }
  }
}

// ---------- x transpose ----------
__global__ __launch_bounds__(128) void xt_kernel(const float* __restrict__ cvt, float* __restrict__ xTp){
  const int t = blockIdx.x, b = threadIdx.x;
  xTp[t*BB + b]            = cvt[(b*2 + 0)*TT + t];
  xTp[65536 + t*BB + b]    = cvt[(b*2 + 1)*TT + t];
}

// ---------- Kernel 1: encoder GRU — single wave, no barrier (proven r11) ----------
__global__ __launch_bounds__(64) void enc_kernel(
    const float* __restrict__ xTp, const _Float16* __restrict__ whhE,
    const float* __restrict__ Wih, const float* __restrict__ bih,
    const float* __restrict__ bhh, float* __restrict__ xfeatT)
{
  const int b0 = blockIdx.x*16;
  const int l = threadIdx.x, ml = l & 15, q = l >> 4;
  __shared__ __align__(16) _Float16 HpkH[16][24];
  __shared__ __align__(16) _Float16 HpkL[16][24];
  half8 Bw[3];
  #pragma unroll
  for (int c=0;c<3;c++)
    Bw[c] = *(const half8*)(whhE + (16*c + ml)*32 + 8*q);
  float w0r=Wih[ml*2],      w1r=Wih[ml*2+1],      bir=bih[ml],    bhr=bhh[ml];
  float w0z=Wih[(16+ml)*2], w1z=Wih[(16+ml)*2+1], biz=bih[16+ml], bhz=bhh[16+ml];
  float w0n=Wih[(32+ml)*2], w1n=Wih[(32+ml)*2+1], bin_=bih[32+ml], bhn=bhh[32+ml];
  float hm[4] = {0,0,0,0};
  HU Ah, Al; Ah.u = make_uint4(0,0,0,0); Al.u = Ah.u;
  const floatx4 z4 = {0.f,0.f,0.f,0.f};
  floatx4 x0v = *(const floatx4*)(xTp + b0 + 4*q);
  floatx4 x1v = *(const floatx4*)(xTp + 65536 + b0 + 4*q);
  for (int t=0;t<TT;t++){
    const int tn = (t < 511) ? t+1 : t;
    floatx4 x0n = *(const floatx4*)(xTp + tn*BB + b0 + 4*q);
    floatx4 x1n = *(const floatx4*)(xTp + 65536 + tn*BB + b0 + 4*q);
    floatx4 C[3];
    #pragma unroll
    for (int c=0;c<3;c++){
      C[c] = MFMA16(Al.h, Bw[c], z4);
      C[c] = MFMA16(Ah.h, Bw[c], C[c]);
    }
    float4 hv4;
    #pragma unroll
    for (int r=0;r<4;r++){
      float xb0 = x0v[r], xb1 = x1v[r];
      float rr = sigm(fmaf(w0r,xb0,fmaf(w1r,xb1,bir)) + C[0][r] + bhr);
      float zz = sigm(fmaf(w0z,xb0,fmaf(w1z,xb1,biz)) + C[1][r] + bhz);
      float nn = tanh_fast(fmaf(w0n,xb0,fmaf(w1n,xb1,bin_)) + rr*(C[2][r] + bhn));
      float hn = nn + zz*(hm[r] - nn);
      hm[r] = hn;
      _Float16 hh = (_Float16)hn;
      _Float16 hl = (_Float16)(hn - (float)hh);
      HpkH[4*q + r][ml] = hh;
      HpkL[4*q + r][ml] = hl;
      ((float*)&hv4)[r] = hn;
    }
    *(float4*)(xfeatT + ((size_t)ml*TT + t)*BB + b0 + 4*q) = hv4;
    if (q < 2){
      Ah.u = *(const uint4*)&HpkH[ml][8*q];
      Al.u = *(const uint4*)&HpkL[ml][8*q];
    } else { Ah.u = make_uint4(0,0,0,0); Al.u = Ah.u; }
    x0v = x0n; x1v = x1n;
  }
}

// ---------- Kernel 2 (fallback path): g1 backward (unchanged, proven) ----------
__global__ __launch_bounds__(128) void g1b_kernel(
    const float* __restrict__ xT, const _Float16* __restrict__ whh_h,
    const float* __restrict__ wih, const float* __restrict__ bih,
    const float* __restrict__ bhh, _Float16* __restrict__ trace)
{
  const int f = blockIdx.x, b0 = blockIdx.y*16;
  const int wid = threadIdx.x >> 6, l = threadIdx.x & 63, ml = l & 15, q = l >> 4;
  __shared__ unsigned int Hpk[2][16][36];
  half8 Bw[3];
  #pragma unroll
  for (int i=0;i<3;i++){
    int tc = 2*i + wid;
    Bw[i] = *(const half8*)(whh_h + (size_t)f*3072 + (16*tc + ml)*32 + 8*q);
  }
  const int j = 16*wid + ml, base = f*96;
  float wir=wih[base+j], wiz=wih[base+32+j], win=wih[base+64+j];
  float br_=bih[base+j]+bhh[base+j];
  float bz_=bih[base+32+j]+bhh[base+32+j];
  float bin_=bih[base+64+j], bhn_=bhh[base+64+j];
  float hm[4] = {0,0,0,0};
  HU Ah, Al; Ah.u = make_uint4(0,0,0,0); Al.u = Ah.u;
  const floatx4 z4 = {0.f,0.f,0.f,0.f};
  int pp = 0;
  floatx4 xv = *(const floatx4*)(xT + ((size_t)f*TT + 511)*BB + b0 + 4*q);
  const int dostore = (wid == (q >> 1));
  for (int s=0;s<512;s++){
    const int t = 511 - s;
    const int tn = (s < 511) ? t-1 : t;
    floatx4 xnx = *(const floatx4*)(xT + ((size_t)f*TT + tn)*BB + b0 + 4*q);
    floatx4 C[3];
    #pragma unroll
    for (int i=0;i<3;i++){
      C[i] = MFMA16(Al.h, Bw[i], z4);
      C[i] = MFMA16(Ah.h, Bw[i], C[i]);
    }
    #pragma unroll
    for (int r=0;r<4;r++){
      float xb = xv[r];
      float rr = sigm(fmaf(wir, xb, br_) + C[0][r]);
      float zz = sigm(fmaf(wiz, xb, bz_) + C[1][r]);
      float nn = tanh_fast(fmaf(win, xb, bin_) + rr*(C[2][r] + bhn_));
      float hn = nn + zz*(hm[r] - nn);
      hm[r] = hn;
      Hpk[pp][4*q + r][j] = packhl(hn);
    }
    __syncthreads();
    {
      uint4 P0 = *(const uint4*)&Hpk[pp][ml][8*q];
      uint4 P1 = *(const uint4*)&Hpk[pp][ml][8*q + 4];
      unpackAB(P0, P1, Ah, Al);
    }
    if (dostore)
      *(uint4*)(trace + (((size_t)(f*BB + b0 + ml))*TT + t)*32 + 8*q) = Ah.u;
    pp ^= 1;
    xv = xnx;
  }
}

// ---------- Kernel 2b (big-ws): g1 bwd+fwd — 2 waves, LIGHT barrier (proven r12) ----------
__global__ __launch_bounds__(128) void g1bf_kernel(
    const float* __restrict__ xT,
    const _Float16* __restrict__ whhB_h, const float* __restrict__ wihB,
    const float* __restrict__ bihB, const float* __restrict__ bhhB,
    const _Float16* __restrict__ whhF_h, const float* __restrict__ wihF,
    const float* __restrict__ bihF, const float* __restrict__ bhhF,
    _Float16* __restrict__ traceB, _Float16* __restrict__ traceF)
{
  const int f = blockIdx.x, b0 = blockIdx.y*16, dir = blockIdx.z;
  const _Float16* whh_h = dir ? whhF_h : whhB_h;
  const float* wih = dir ? wihF : wihB;
  const float* bih = dir ? bihF : bihB;
  const float* bhh = dir ? bhhF : bhhB;
  _Float16* trace = dir ? traceF : traceB;
  const int wid = threadIdx.x >> 6, l = threadIdx.x & 63, ml = l & 15, q = l >> 4;
  __shared__ __align__(16) _Float16 HpkH[2][16][40];
  __shared__ __align__(16) _Float16 HpkL[2][16][40];
  half8 Bw[3];
  #pragma unroll
  for (int i=0;i<3;i++){
    int tc = 2*i + wid;
    Bw[i] = *(const half8*)(whh_h + (size_t)f*3072 + (16*tc + ml)*32 + 8*q);
  }
  const int j = 16*wid + ml, base = f*96;
  float wir=wih[base+j], wiz=wih[base+32+j], win=wih[base+64+j];
  float br_=bih[base+j]+bhh[base+j];
  float bz_=bih[base+32+j]+bhh[base+32+j];
  float bin_=bih[base+64+j], bhn_=bhh[base+64+j];
  float hm[4] = {0,0,0,0};
  HU Ah, Al; Ah.u = make_uint4(0,0,0,0); Al.u = Ah.u;
  const floatx4 z4 = {0.f,0.f,0.f,0.f};
  int pp = 0;
  const int tfirst = dir ? 0 : 511;
  floatx4 xv = *(const floatx4*)(xT + ((size_t)f*TT + tfirst)*BB + b0 + 4*q);
  const int dostore = (wid == (q >> 1));
  for (int s=0;s<512;s++){
    const int t  = dir ? s : 511 - s;
    const int sn = (s < 511) ? s+1 : s;
    const int tn = dir ? sn : 511 - sn;
    floatx4 xnx = *(const floatx4*)(xT + ((size_t)f*TT + tn)*BB + b0 + 4*q);
    floatx4 C[3];
    #pragma unroll
    for (int i=0;i<3;i++){
      C[i] = MFMA16(Al.h, Bw[i], z4);
      C[i] = MFMA16(Ah.h, Bw[i], C[i]);
    }
    #pragma unroll
    for (int r=0;r<4;r++){
      float xb = xv[r];
      float rr = sigm(fmaf(wir, xb, br_) + C[0][r]);
      float zz = sigm(fmaf(wiz, xb, bz_) + C[1][r]);
      float nn = tanh_fast(fmaf(win, xb, bin_) + rr*(C[2][r] + bhn_));
      float hn = nn + zz*(hm[r] - nn);
      hm[r] = hn;
      _Float16 hh = (_Float16)hn;
      _Float16 hl = (_Float16)(hn - (float)hh);
      HpkH[pp][4*q + r][j] = hh;
      HpkL[pp][4*q + r][j] = hl;
    }
    lb();
    Ah.u = *(const uint4*)&HpkH[pp][ml][8*q];
    Al.u = *(const uint4*)&HpkL[pp][ml][8*q];
    if (dostore)
      *(uint4*)(trace + (((size_t)(f*BB + b0 + ml))*TT + t)*32 + 8*q) = Ah.u;
    pp ^= 1;
    xv = xnx;
  }
}

// ---------- Kernel 3 (fallback path): fused g1f + g2 (unchanged, proven) ----------
__global__ __launch_bounds__(128) void g2_kernel(
    const float* __restrict__ xT,
    const _Float16* __restrict__ wh1_h, const float* __restrict__ wih1,
    const float* __restrict__ bih1, const float* __restrict__ bhh1,
    const _Float16* __restrict__ wh2_h, const _Float16* __restrict__ w2i_h,
    const float* __restrict__ bih2, const float* __restrict__ bhh2,
    _Float16* __restrict__ trace)
{
  const int f = blockIdx.x, b0 = blockIdx.y*16;
  const int wid = threadIdx.x >> 6, l = threadIdx.x & 63, ml = l & 15, q = l >> 4;
  __shared__ unsigned int Hpk1[2][16][36];
  __shared__ unsigned int Hpk2[2][16][36];
  half8 B1[3], Bh2[3], Bx0[3], Bx1[3];
  #pragma unroll
  for (int i=0;i<3;i++){
    int tc = 2*i + wid;
    B1[i]  = *(const half8*)(wh1_h + (size_t)f*3072 + (16*tc + ml)*32 + 8*q);
    Bh2[i] = *(const half8*)(wh2_h + (size_t)f*3072 + (16*tc + ml)*32 + 8*q);
    Bx0[i] = *(const half8*)(w2i_h + (size_t)f*6144 + (16*tc + ml)*64 + 8*q);
    Bx1[i] = *(const half8*)(w2i_h + (size_t)f*6144 + (16*tc + ml)*64 + 32 + 8*q);
  }
  const int j = 16*wid + ml, base = f*96;
  float wir=wih1[base+j], wiz=wih1[base+32+j], win=wih1[base+64+j];
  float br1_=bih1[base+j]+bhh1[base+j];
  float bz1_=bih1[base+32+j]+bhh1[base+32+j];
  float bin1_=bih1[base+64+j], bhn1_=bhh1[base+64+j];
  float br2_=bih2[base+j]+bhh2[base+j];
  float bz2_=bih2[base+32+j]+bhh2[base+32+j];
  float bin2_=bih2[base+64+j], bhn2_=bhh2[base+64+j];
  float h1[4] = {0,0,0,0};
  float h2[4] = {0,0,0,0};
  HU A1h, A1l, A2h, A2l;
  A1h.u = make_uint4(0,0,0,0); A1l.u = A1h.u; A2h.u = A1h.u; A2l.u = A1h.u;
  const floatx4 z4 = {0.f,0.f,0.f,0.f};
  const size_t rowb = ((size_t)(f*BB + b0 + ml))*TT;
  const int dostore = (wid == (q >> 1));

  {
    floatx4 x0v = *(const floatx4*)(xT + (size_t)f*TT*BB + b0 + 4*q);
    #pragma unroll
    for (int r=0;r<4;r++){
      float xb = x0v[r];
      float rr = sigm(fmaf(wir, xb, br1_));
      float zz = sigm(fmaf(wiz, xb, bz1_));
      float nn = tanh_fast(fmaf(win, xb, bin1_) + rr*bhn1_);
      float hn = (1.f - zz)*nn;
      h1[r] = hn;
      Hpk1[0][4*q + r][j] = packhl(hn);
    }
    __syncthreads();
    uint4 P0 = *(const uint4*)&Hpk1[0][ml][8*q];
    uint4 P1 = *(const uint4*)&Hpk1[0][ml][8*q + 4];
    unpackAB(P0, P1, A1h, A1l);
  }
  int pp = 1;
  uint4 Ub = *(const uint4*)(trace + (rowb + 0)*32 + 8*q);
  floatx4 xv = *(const floatx4*)(xT + ((size_t)f*TT + 1)*BB + b0 + 4*q);
  for (int t=0;t<512;t++){
    const int tn1 = (t < 511) ? t+1 : t;
    const int tn2 = (t < 510) ? t+2 : 511;
    uint4 Ubn = *(const uint4*)(trace + (rowb + tn1)*32 + 8*q);
    floatx4 xnx = *(const floatx4*)(xT + ((size_t)f*TT + tn2)*BB + b0 + 4*q);
    floatx4 C1[3];
    #pragma unroll
    for (int i=0;i<3;i++){
      C1[i] = MFMA16(A1l.h, B1[i], z4);
      C1[i] = MFMA16(A1h.h, B1[i], C1[i]);
    }
    HU Abw; Abw.u = Ub;
    floatx4 Cr, Cz, Cnh, Cnx;
    Cr = MFMA16(A2l.h, Bh2[0], z4); Cr = MFMA16(A2h.h, Bh2[0], Cr);
    Cr = MFMA16(A1l.h, Bx0[0], Cr); Cr = MFMA16(A1h.h, Bx0[0], Cr);
    Cr = MFMA16(Abw.h, Bx1[0], Cr);
    Cz = MFMA16(A2l.h, Bh2[1], z4); Cz = MFMA16(A2h.h, Bh2[1], Cz);
    Cz = MFMA16(A1l.h, Bx0[1], Cz); Cz = MFMA16(A1h.h, Bx0[1], Cz);
    Cz = MFMA16(Abw.h, Bx1[1], Cz);
    Cnh = MFMA16(A2l.h, Bh2[2], z4); Cnh = MFMA16(A2h.h, Bh2[2], Cnh);
    Cnx = MFMA16(A1l.h, Bx0[2], z4); Cnx = MFMA16(A1h.h, Bx0[2], Cnx);
    Cnx = MFMA16(Abw.h, Bx1[2], Cnx);
    #pragma unroll
    for (int r=0;r<4;r++){
      float xb = xv[r];
      float rr1 = sigm(fmaf(wir, xb, br1_) + C1[0][r]);
      float zz1 = sigm(fmaf(wiz, xb, bz1_) + C1[1][r]);
      float nn1 = tanh_fast(fmaf(win, xb, bin1_) + rr1*(C1[2][r] + bhn1_));
      float hn1 = nn1 + zz1*(h1[r] - nn1);
      h1[r] = hn1;
      Hpk1[pp][4*q + r][j] = packhl(hn1);

      float rr2 = sigm(Cr[r] + br2_);
      float zz2 = sigm(Cz[r] + bz2_);
      float nn2 = tanh_fast(Cnx[r] + bin2_ + rr2*(Cnh[r] + bhn2_));
      float hn2 = nn2 + zz2*(h2[r] - nn2);
      h2[r] = hn2;
      Hpk2[pp][4*q + r][j] = packhl(hn2);
    }
    __syncthreads();
    {
      uint4 P0 = *(const uint4*)&Hpk1[pp][ml][8*q];
      uint4 P1 = *(const uint4*)&Hpk1[pp][ml][8*q + 4];
      unpackAB(P0, P1, A1h, A1l);
      uint4 Q0 = *(const uint4*)&Hpk2[pp][ml][8*q];
      uint4 Q1 = *(const uint4*)&Hpk2[pp][ml][8*q + 4];
      unpackAB(Q0, Q1, A2h, A2l);
    }
    if (dostore)
      *(uint4*)(trace + (rowb + t)*32 + 8*q) = A2h.u;
    Ub = Ubn; xv = xnx; pp ^= 1;
  }
}

// ---------- Kernel 3b (big-ws): g2 only — 2 waves, LIGHT barrier (proven r12) ----------
__global__ __launch_bounds__(128) void g2f_kernel(
    const _Float16* __restrict__ wh2_h, const _Float16* __restrict__ w2i_h,
    const float* __restrict__ bih2, const float* __restrict__ bhh2,
    const _Float16* __restrict__ traceF, _Float16* __restrict__ traceB)
{
  const int f = blockIdx.x, b0 = blockIdx.y*16;
  const int wid = threadIdx.x >> 6, l = threadIdx.x & 63, ml = l & 15, q = l >> 4;
  __shared__ __align__(16) _Float16 HpkH[2][16][40];
  __shared__ __align__(16) _Float16 HpkL[2][16][40];
  half8 Bh2[3], Bx0[3], Bx1[3];
  #pragma unroll
  for (int i=0;i<3;i++){
    int tc = 2*i + wid;
    Bh2[i] = *(const half8*)(wh2_h + (size_t)f*3072 + (16*tc + ml)*32 + 8*q);
    Bx0[i] = *(const half8*)(w2i_h + (size_t)f*6144 + (16*tc + ml)*64 + 8*q);
    Bx1[i] = *(const half8*)(w2i_h + (size_t)f*6144 + (16*tc + ml)*64 + 32 + 8*q);
  }
  const int j = 16*wid + ml, base = f*96;
  float br2_=bih2[base+j]+bhh2[base+j];
  float bz2_=bih2[base+32+j]+bhh2[base+32+j];
  float bin2_=bih2[base+64+j], bhn2_=bhh2[base+64+j];
  float h2[4] = {0,0,0,0};
  HU A2h, A2l; A2h.u = make_uint4(0,0,0,0); A2l.u = A2h.u;
  const floatx4 z4 = {0.f,0.f,0.f,0.f};
  const size_t rowb = ((size_t)(f*BB + b0 + ml))*TT;
  const int dostore = (wid == (q >> 1));
  int pp = 0;
  uint4 F0 = *(const uint4*)(traceF + (rowb + 0)*32 + 8*q);
  uint4 F1 = *(const uint4*)(traceF + (rowb + 1)*32 + 8*q);
  uint4 B0 = *(const uint4*)(traceB + (rowb + 0)*32 + 8*q);
  uint4 B1 = *(const uint4*)(traceB + (rowb + 1)*32 + 8*q);
  for (int t=0;t<512;t++){
    const int tn = (t < 510) ? t+2 : 511;
    uint4 F2 = *(const uint4*)(traceF + (rowb + tn)*32 + 8*q);
    uint4 B2 = *(const uint4*)(traceB + (rowb + tn)*32 + 8*q);
    HU AF; AF.u = F0;
    HU AB; AB.u = B0;
    floatx4 Cr, Cz, Cnh, Cnx;
    {
      floatx4 CrA = MFMA16(A2l.h, Bh2[0], z4); CrA = MFMA16(A2h.h, Bh2[0], CrA);
      floatx4 CrB = MFMA16(AF.h, Bx0[0], z4);  CrB = MFMA16(AB.h, Bx1[0], CrB);
      Cr = CrA + CrB;
      floatx4 CzA = MFMA16(A2l.h, Bh2[1], z4); CzA = MFMA16(A2h.h, Bh2[1], CzA);
      floatx4 CzB = MFMA16(AF.h, Bx0[1], z4);  CzB = MFMA16(AB.h, Bx1[1], CzB);
      Cz = CzA + CzB;
      Cnh = MFMA16(A2l.h, Bh2[2], z4); Cnh = MFMA16(A2h.h, Bh2[2], Cnh);
      Cnx = MFMA16(AF.h, Bx0[2], z4);  Cnx = MFMA16(AB.h, Bx1[2], Cnx);
    }
    #pragma unroll
    for (int r=0;r<4;r++){
      float rr2 = sigm(Cr[r] + br2_);
      float zz2 = sigm(Cz[r] + bz2_);
      float nn2 = tanh_fast(Cnx[r] + bin2_ + rr2*(Cnh[r] + bhn2_));
      float hn2 = nn2 + zz2*(h2[r] - nn2);
      h2[r] = hn2;
      _Float16 hh = (_Float16)hn2;
      _Float16 hl = (_Float16)(hn2 - (float)hh);
      HpkH[pp][4*q + r][j] = hh;
      HpkL[pp][4*q + r][j] = hl;
    }
    lb();
    A2h.u = *(const uint4*)&HpkH[pp][ml][8*q];
    A2l.u = *(const uint4*)&HpkL[pp][ml][8*q];
    if (dostore)
      *(uint4*)(traceB + (rowb + t)*32 + 8*q) = A2h.u;   // u2 over consumed u1b[t]
    F0 = F1; F1 = F2; B0 = B1; B1 = B2; pp ^= 1;
  }
}

// ---------- Kernel 4: convT chain via MFMA, W=64 tile — SPLIT ACC CHAINS ----------
#define UTP 40
#define C3P 72
#define C2P 136
__global__ __launch_bounds__(256) void conv_kernel(
    const _Float16* __restrict__ u2,
    const _Float16* __restrict__ w3T, const float* __restrict__ b3,
    const _Float16* __restrict__ w2T, const float* __restrict__ b2,
    const float* __restrict__ w1, const float* __restrict__ b1,
    void* __restrict__ outv, const int* __restrict__ flag)
{
  const int t0 = blockIdx.x * 64;
  const int b  = blockIdx.y;
  const int f  = blockIdx.z;
  const int tid = threadIdx.x;
  const int w = tid >> 6, l = tid & 63, ml = l & 15, q = l >> 4;

  __shared__ __align__(16) _Float16 utb[84][UTP];
  __shared__ __align__(16) _Float16 c3T[84][C3P];
  __shared__ __align__(16) _Float16 c2T[68][C2P];
  __shared__ float red[4][64];

  const _Float16* urow = u2 + ((size_t)(f*BB + b)*TT)*32;
  const floatx4 z4 = {0.f,0.f,0.f,0.f};

  for (int k = tid; k < 76*4; k += 256){
    int n = k >> 2, seg = k & 3;
    int tg = t0 - 6 + n;
    uint4 v = make_uint4(0,0,0,0);
    if (tg >= 0 && tg < TT) v = *(const uint4*)(urow + (size_t)tg*32 + seg*8);
    *(uint4*)&utb[n][seg*8] = v;
  }
  __syncthreads();

  // phase B: c3 — 3+2 tap split (two independent MFMA chains)
  {
    half8 A3[5];
    #pragma unroll
    for (int jj=0;jj<5;jj++)
      A3[jj] = *(const half8*)(w3T + (((size_t)f*5 + jj)*64 + 16*w + ml)*32 + 8*q);
    float bv[4];
    #pragma unroll
    for (int r=0;r<4;r++) bv[r] = b3[f*64 + 16*w + 4*q + r];
    #pragma unroll
    for (int nt=0;nt<5;nt++){
      floatx4 accA = z4, accB = z4;
      #pragma unroll
      for (int jj=0;jj<5;jj++){
        half8 Bb = *(const half8*)&utb[16*nt + ml + 4 - jj][8*q];
        if (jj < 3) accA = MFMA16(A3[jj], Bb, accA);
        else        accB = MFMA16(A3[jj], Bb, accB);
      }
      floatx4 acc = accA + accB;
      int tm = 16*nt + ml;
      if (tm < 72){
        int G = t0 - 4 + tm;
        unsigned int pk[2];
        #pragma unroll
        for (int h=0;h<2;h++){
          float v0 = acc[2*h]   + bv[2*h];   v0 = lrelu(v0);
          float v1 = acc[2*h+1] + bv[2*h+1]; v1 = lrelu(v1);
          if (G < 0 || G >= TT){ v0 = 0.f; v1 = 0.f; }
          union { _Float16 hh; unsigned short s; } c0, c1;
          c0.hh = (_Float16)v0; c1.hh = (_Float16)v1;
          pk[h] = (unsigned int)c0.s | ((unsigned int)c1.s << 16);
        }
        *(uint2*)&c3T[tm][16*w + 4*q] = make_uint2(pk[0], pk[1]);
      }
    }
  }
  __syncthreads();

  // phase C: c2 — per-ci-half partials (four independent 5-deep chains instead
  // of two 10-deep)
  {
    half8 A2f[5][2][2];
    #pragma unroll
    for (int jj=0;jj<5;jj++)
      #pragma unroll
      for (int ch=0;ch<2;ch++)
        #pragma unroll
        for (int mi=0;mi<2;mi++)
          A2f[jj][ch][mi] = *(const half8*)(w2T + (((size_t)f*5 + jj)*128 + 16*(2*w+mi) + ml)*64 + 32*ch + 8*q);
    float bv2[2][4];
    #pragma unroll
    for (int mi=0;mi<2;mi++)
      #pragma unroll
      for (int r=0;r<4;r++) bv2[mi][r] = b2[f*128 + 16*(2*w+mi) + 4*q + r];
    #pragma unroll
    for (int nt=0;nt<5;nt++){
      floatx4 a0A = z4, a0B = z4, a1A = z4, a1B = z4;
      #pragma unroll
      for (int jj=0;jj<5;jj++){
        half8 Bb0 = *(const half8*)&c3T[16*nt + ml + 4 - jj][8*q];
        half8 Bb1 = *(const half8*)&c3T[16*nt + ml + 4 - jj][32 + 8*q];
        a0A = MFMA16(A2f[jj][0][0], Bb0, a0A);
        a0B = MFMA16(A2f[jj][1][0], Bb1, a0B);
        a1A = MFMA16(A2f[jj][0][1], Bb0, a1A);
        a1B = MFMA16(A2f[jj][1][1], Bb1, a1B);
      }
      floatx4 a0 = a0A + a0B, a1 = a1A + a1B;
      int p = 16*nt + ml;
      if (p < 68){
        int G = t0 - 2 + p;
        #pragma unroll
        for (int mi=0;mi<2;mi++){
          unsigned int pk[2];
          #pragma unroll
          for (int h=0;h<2;h++){
            float v0 = (mi ? a1[2*h]   : a0[2*h])   + bv2[mi][2*h];   v0 = lrelu(v0);
            float v1 = (mi ? a1[2*h+1] : a0[2*h+1]) + bv2[mi][2*h+1]; v1 = lrelu(v1);
            if (G < 0 || G >= TT){ v0 = 0.f; v1 = 0.f; }
            union { _Float16 hh; unsigned short s; } c0, c1;
            c0.hh = (_Float16)v0; c1.hh = (_Float16)v1;
            pk[h] = (unsigned int)c0.s | ((unsigned int)c1.s << 16);
          }
          *(uint2*)&c2T[p][16*(2*w+mi) + 4*q] = make_uint2(pk[0], pk[1]);
        }
      }
    }
  }
  __syncthreads();

  // phase D: c1 — 4 independent fmaf partial chains (was one 160-deep chain)
  {
    const int tl = tid & 63, cg = tid >> 6;
    const float* wp = w1 + ((size_t)f*128 + cg*32)*5;
    float p0 = 0.f, p1 = 0.f, p2 = 0.f, p3 = 0.f;
    #pragma unroll
    for (int jj=0;jj<5;jj++){
      int row = tl + 4 - jj;
      union { uint4 u; _Float16 h[8]; } u0, u1, u2_, u3;
      u0.u  = *(const uint4*)&c2T[row][cg*32];
      u1.u  = *(const uint4*)&c2T[row][cg*32 + 8];
      u2_.u = *(const uint4*)&c2T[row][cg*32 + 16];
      u3.u  = *(const uint4*)&c2T[row][cg*32 + 24];
      #pragma unroll
      for (int i=0;i<8;i++){
        p0 = fmaf(wp[i*5 + jj],      (float)u0.h[i],  p0);
        p1 = fmaf(wp[(8+i)*5 + jj],  (float)u1.h[i],  p1);
        p2 = fmaf(wp[(16+i)*5 + jj], (float)u2_.h[i], p2);
        p3 = fmaf(wp[(24+i)*5 + jj], (float)u3.h[i],  p3);
      }
    }
    red[cg][tl] = (p0 + p1) + (p2 + p3);
  }
  __syncthreads();
  if (tid < 64){
    float s = b1[f] + red[0][tid] + red[1][tid] + red[2][tid] + red[3][tid];
    s = lrelu(s);
    size_t oi = ((size_t)b*TT + t0 + tid)*FF + f;
    if (*flag) ((unsigned short*)outv)[oi] = f2bf(s);
    else       ((float*)outv)[oi] = s;
  }
}

extern "C" void kernel_launch(void* const* d_in, const int* in_sizes, int n_in,
                              void* d_out, int out_size, void* d_ws, size_t ws_size,
                              hipStream_t stream)
{
  static const int esz[23] = {
    131072,
    96, 768, 48, 48,
    1536, 49152, 1536, 1536,
    1536, 49152, 1536, 1536,
    98304, 49152, 1536, 1536,
    163840, 1024,
    655360, 2048,
    10240, 16
  };
  const size_t NEED = (size_t)16*1024*1024 + (size_t)64*1024*1024;

  float diag = 0.f;
  if (n_in != 23) diag = 2000.f + n_in;
  else {
    for (int i=0;i<23;i++) if (in_sizes[i] != esz[i]) { diag = 1000.f + i; break; }
    if (diag == 0.f && ws_size < NEED) diag = 500.f + (float)(ws_size >> 20);
  }
  if (diag != 0.f){
    hipLaunchKernelGGL(fill_kernel, dim3((out_size+255)/256), dim3(256), 0, stream,
                       (unsigned short*)d_out, out_size, diag);
    return;
  }

  float* cvt = (float*)d_ws;
  int* flagp = (int*)((char*)d_ws + (5ull<<20));
  float* maxbuf = (float*)((char*)d_ws + (5ull<<20) + 256);
  _Float16* h16 = (_Float16*)((char*)d_ws + (6ull<<20));
  float* xTp = (float*)((char*)d_ws + (9ull<<20));
  float* xfeatT = (float*)((char*)d_ws + (10ull<<20));
  _Float16* trace = (_Float16*)((char*)d_ws + (14ull<<20));     // u1b -> u2 (64 MB)
  _Float16* traceF = (_Float16*)((char*)d_ws + (80ull<<20));    // u1f (64 MB, big-ws only)
  const bool bigws = (ws_size >= (145ull<<20));

  CvtArgs a;
  int ofs = 0;
  for (int i=0;i<23;i++){ a.p[i] = d_in[i]; a.sz[i] = esz[i]; a.ofs[i] = ofs; ofs += esz[i]; }
  const float* c[23];
  for (int i=0;i<23;i++) c[i] = cvt + a.ofs[i];

  hipLaunchKernelGGL(detect1_kernel, dim3(32), dim3(256), 0, stream,
                     (const unsigned short*)d_in[0], maxbuf);
  hipLaunchKernelGGL(detect2_kernel, dim3(1), dim3(64), 0, stream, maxbuf, flagp);
  hipLaunchKernelGGL(convert_kernel, dim3(23, 40), dim3(256), 0, stream, a, flagp, cvt);
  hipLaunchKernelGGL(prep16_kernel, dim3(2560, 7), dim3(256), 0, stream,
                     cvt, h16, a.ofs[6], a.ofs[10], a.ofs[14], a.ofs[13],
                     a.ofs[17], a.ofs[19], a.ofs[2]);
  hipLaunchKernelGGL(xt_kernel, dim3(TT), dim3(BB), 0, stream, cvt, xTp);
  hipLaunchKernelGGL(enc_kernel, dim3(BB/16), dim3(64), 0, stream,
                     xTp, h16 + 1064960, c[1], c[3], c[4], xfeatT);
  if (bigws){
    hipLaunchKernelGGL(g1bf_kernel, dim3(FF, 8, 2), dim3(128), 0, stream,
                       xfeatT,
                       h16 + 49152, c[9], c[11], c[12],    // bwd
                       h16 + 0,     c[5], c[7],  c[8],     // fwd
                       trace, traceF);
    hipLaunchKernelGGL(g2f_kernel, dim3(FF, 8), dim3(128), 0, stream,
                       h16 + 98304, h16 + 147456, c[15], c[16],
                       traceF, trace);
  } else {
    hipLaunchKernelGGL(g1b_kernel, dim3(FF, 8), dim3(128), 0, stream,
                       xfeatT, h16 + 49152, c[9], c[11], c[12], trace);
    hipLaunchKernelGGL(g2_kernel, dim3(FF, 8), dim3(128), 0, stream,
                       xfeatT, h16 + 0, c[5], c[7], c[8],
                       h16 + 98304, h16 + 147456, c[15], c[16], trace);
  }
  hipLaunchKernelGGL(conv_kernel, dim3(TT/64, BB, FF), dim3(256), 0, stream,
                     trace, h16 + 245760, c[18], h16 + 409600, c[20], c[21], c[22],
                     d_out, flagp);
}